// Round 2
// baseline (362.188 us; speedup 1.0000x reference)
//
#include <hip/hip_runtime.h>
#include <stdint.h>

typedef uint32_t u32;
typedef uint64_t u64;

#define NB 4
#define NA 9
#define NH 34
#define NW 60
#define HW (NH*NW)            // 2040
#define NBOX (NA*HW)          // 18360
#define PRE_NMS 3000
#define POST_NMS 300
#define NBUCKET 4096
#define CAP 4096
#define NTH 1024
#define PER 18                // 18*1024 = 18432 >= 18360
#define MWORDS 48             // 48*64 = 3072 >= 3000 candidate bits per mask row

// Anchor widths/heights (f64->f32 roundings, matching np.array(..., float32)).
__device__ __constant__ float c_aw[9] = {
  45.254833995939045f, 64.0f,  90.50966799187808f,
  90.50966799187808f,  128.0f, 181.01933598375617f,
  181.01933598375617f, 256.0f, 362.03867196751233f };
__device__ __constant__ float c_ah[9] = {
  90.50966799187808f,  64.0f,  45.254833995939045f,
  181.01933598375617f, 128.0f, 90.50966799187808f,
  362.03867196751233f, 256.0f, 181.01933598375617f };

__device__ __forceinline__ u64 shfl64(u64 v, int src) {
  u32 lo = (u32)__shfl((int)(u32)(v & 0xffffffffull), src);
  u32 hi = (u32)__shfl((int)(u32)(v >> 32), src);
  return ((u64)hi << 32) | lo;
}

// ---------------------------------------------------------------------------
// K1: histogram top-3000 select + bitonic sort + decode -> ws boxes
// ---------------------------------------------------------------------------
__global__ void __launch_bounds__(NTH)
topk_sort_decode_kernel(const float* __restrict__ scores,
                        const float* __restrict__ deltas,
                        float4* __restrict__ boxes_ws)
{
  __shared__ __align__(16) char smem[16384 + 32768 + 4096];
  u32* s_hist = (u32*)smem;
  u64* s_cand = (u64*)(smem + 16384);
  u32* s_sfx  = (u32*)(smem + 16384 + 32768);
  __shared__ u32 s_meta[4];

  const int tid = threadIdx.x;
  const int b   = blockIdx.x;
  const float* sc = scores + b * NBOX;

  for (int t = tid; t < NBUCKET; t += NTH) s_hist[t] = 0;
  if (tid < 4) s_meta[tid] = 0;
  __syncthreads();

  // histogram
  for (int m = 0; m < PER; ++m) {
    int i = tid + m * NTH;
    if (i < NBOX) {
      float s = sc[i];
      int bk = (int)(s * (float)NBUCKET);
      bk = bk < 0 ? 0 : (bk > NBUCKET - 1 ? NBUCKET - 1 : bk);
      atomicAdd(&s_hist[bk], 1u);
    }
  }
  __syncthreads();

  // 4-bucket group sums + inclusive suffix scan over 1024 groups
  {
    u32 g = s_hist[4*tid] + s_hist[4*tid+1] + s_hist[4*tid+2] + s_hist[4*tid+3];
    s_sfx[tid] = g;
  }
  __syncthreads();
  for (int d = 1; d < NTH; d <<= 1) {
    u32 v = (tid + d < NTH) ? s_sfx[tid + d] : 0u;
    __syncthreads();
    s_sfx[tid] += v;
    __syncthreads();
  }

  // threshold bucket T
  {
    u32 sg  = s_sfx[tid];
    u32 sgn = (tid < NTH - 1) ? s_sfx[tid + 1] : 0u;
    if (sg >= PRE_NMS && sgn < PRE_NMS) {
      u32 c = sgn;
      for (int t = 4 * tid + 3; t >= 4 * tid; --t) {
        c += s_hist[t];
        if (c >= PRE_NMS) { s_meta[0] = (u32)t; s_meta[1] = c; break; }
      }
    }
  }
  __syncthreads();
  const u32 T = s_meta[0];

  // compact candidates
  for (int m = 0; m < PER; ++m) {
    int i = tid + m * NTH;
    if (i < NBOX) {
      float s = sc[i];
      int bk = (int)(s * (float)NBUCKET);
      bk = bk < 0 ? 0 : (bk > NBUCKET - 1 ? NBUCKET - 1 : bk);
      if ((u32)bk >= T) {
        u32 pos = atomicAdd(&s_meta[2], 1u);
        if (pos < CAP) {
          u64 key = ((u64)__float_as_uint(s) << 32) | (u32)(~(u32)i);
          s_cand[pos] = key;
        }
      }
    }
  }
  __syncthreads();
  {
    u32 C = s_meta[2]; if (C > CAP) C = CAP;
    for (u32 p = C + tid; p < CAP; p += NTH) s_cand[p] = 0ull;
  }

  // bitonic sort 4096 u64, descending
  for (int kk = 2; kk <= CAP; kk <<= 1) {
    for (int j = kk >> 1; j > 0; j >>= 1) {
      __syncthreads();
      #pragma unroll
      for (int m = 0; m < 2; ++m) {
        int t = tid + m * NTH;
        int i = ((t & ~(j - 1)) << 1) | (t & (j - 1));
        int p = i | j;
        u64 a  = s_cand[i];
        u64 bb = s_cand[p];
        bool desc = (i & kk) == 0;
        bool sw = desc ? (a < bb) : (a > bb);
        if (sw) { s_cand[i] = bb; s_cand[p] = a; }
      }
    }
  }
  __syncthreads();

  // decode top-3000 -> ws
  const float* dl = deltas + b * (4 * NA * HW);
  #pragma unroll
  for (int m = 0; m < 3; ++m) {
    int k = tid + m * NTH;
    if (k < PRE_NMS) {
      u64 key = s_cand[k];
      int idx = (int)(~(u32)key);
      int a = idx / HW;
      int r = idx - a * HW;
      int h = r / NW;
      int w = r - h * NW;
      const float* dp = dl + (4 * a) * HW + r;
      float tx = dp[0];
      float ty = dp[HW];
      float tw = dp[2 * HW];
      float th = dp[3 * HW];
      float aw = c_aw[a], ah = c_ah[a];
      float ctr_x = ((float)w + 0.5f) * 16.0f + tx * aw;
      float ctr_y = ((float)h + 0.5f) * 16.0f + ty * ah;
      float w1 = expf(tw) * aw;
      float h1 = expf(th) * ah;
      float x1 = ctr_x - 0.5f * w1;
      float y1 = ctr_y - 0.5f * h1;
      float x2 = x1 + w1;
      float y2 = y1 + h1;
      x1 = fminf(fmaxf(x1, 0.0f), 959.0f);
      x2 = fminf(fmaxf(x2, 0.0f), 959.0f);
      y1 = fminf(fmaxf(y1, 0.0f), 543.0f);
      y2 = fminf(fmaxf(y2, 0.0f), 543.0f);
      boxes_ws[b * PRE_NMS + k] = make_float4(x1, y1, x2, y2);
    }
  }
}

// ---------------------------------------------------------------------------
// K2: suppression bit-matrix. mask[b][i][c] bit k = IoU(box i, box 64c+k)>0.7
// Full (symmetric) matrix; stale lower-triangle / self bits are harmless
// because the reduce cursor only moves forward.
// ---------------------------------------------------------------------------
__global__ void __launch_bounds__(256)
mask_kernel(const float4* __restrict__ boxes_ws, u64* __restrict__ masks)
{
  const int b = blockIdx.z, c = blockIdx.x;
  const int tid = threadIdx.x;
  __shared__ float4 s_cb[64];
  __shared__ float  s_ca[64];
  if (tid < 64) {
    int j = c * 64 + tid;
    float4 v = (j < PRE_NMS) ? boxes_ws[b * PRE_NMS + j]
                             : make_float4(0.f, 0.f, 0.f, 0.f);
    s_cb[tid] = v;
    s_ca[tid] = (v.z - v.x) * (v.w - v.y);
  }
  __syncthreads();
  int row = blockIdx.y * 250 + tid;
  if (tid < 250 && row < PRE_NMS) {
    float4 r = boxes_ws[b * PRE_NMS + row];
    float ra = (r.z - r.x) * (r.w - r.y);
    u64 word = 0;
    #pragma unroll
    for (int k = 0; k < 64; ++k) {
      float4 cb = s_cb[k];
      float iw = fminf(r.z, cb.z) - fmaxf(r.x, cb.x);
      float ih = fminf(r.w, cb.w) - fmaxf(r.y, cb.y);
      iw = fmaxf(iw, 0.0f);
      ih = fmaxf(ih, 0.0f);
      float inter = iw * ih;
      float uni = ra + s_ca[k] - inter;
      word |= ((u64)(inter > 0.7f * fmaxf(uni, 1e-8f))) << k;
    }
    masks[((size_t)b * PRE_NMS + row) * MWORDS + c] = word;
  }
}

// ---------------------------------------------------------------------------
// K3: serial greedy reduce, chain length = #kept (<=300). Lane w owns removed
// word w in a register. Per step: ballot+ffs+shfl finds next clear bit (all
// suppressed boxes skipped free), OR in kept row's mask (speculatively
// prefetched 1-2 steps ahead).
// ---------------------------------------------------------------------------
__global__ void __launch_bounds__(64)
nms_reduce_kernel(const float4* __restrict__ boxes_ws,
                  const u64* __restrict__ masks,
                  float* __restrict__ out)
{
  const int b = blockIdx.x;
  const int lane = threadIdx.x;
  __shared__ u32 s_kept[POST_NMS];

  // removed bitmap: lane w owns bits [64w, 64w+64). Pre-set bits >= 3000.
  u64 remv;
  if (lane < 46)      remv = 0ull;
  else if (lane == 46) remv = ~((1ull << 56) - 1);   // bits 3000..3007
  else                 remv = ~0ull;                 // lanes 47..63

  const u64* mrow = masks + (size_t)b * PRE_NMS * MWORDS;
  int nk = 0;

  // prefetch state: predicted next-kept rows
  int pj1 = 0, pj2 = -1;
  u64 pr1 = (lane < 47) ? mrow[lane] : 0ull;   // row 0 is always kept first
  u64 pr2 = 0ull;

  int nexti = 0;
  while (nk < POST_NMS) {
    // find next clear bit >= nexti
    u64 m = remv;
    int wn = nexti >> 6, bn = nexti & 63;
    if (lane < wn) m = ~0ull;
    else if (lane == wn && bn) m |= (1ull << bn) - 1;
    u64 bal = __ballot((~m) != 0ull);
    if (bal == 0ull) break;
    int w0 = __ffsll((unsigned long long)bal) - 1;
    u64 mw = shfl64(m, w0);
    int i = (w0 << 6) + (__ffsll((unsigned long long)~mw) - 1);

    // mask row for kept box i (hit the speculative prefetch if possible)
    u64 row;
    if (i == pj1)      row = pr1;
    else if (i == pj2) row = pr2;
    else               row = (lane < 47) ? mrow[(size_t)i * MWORDS + lane] : 0ull;

    if (lane == 0) s_kept[nk] = (u32)i;
    ++nk;

    // speculative prefetch of the next two candidates using PRE-OR remv.
    // Post-OR first clear >= i+1 is provably pj1 (if it survives row i) else
    // >= pj2 — so the match test in the next iteration is exact.
    {
      u64 m2 = remv;
      int wn2 = (i + 1) >> 6, bn2 = (i + 1) & 63;
      if (lane < wn2) m2 = ~0ull;
      else if (lane == wn2 && bn2) m2 |= (1ull << bn2) - 1;
      u64 b2 = __ballot((~m2) != 0ull);
      pj1 = -1; pj2 = -1;
      if (b2) {
        int ww = __ffsll((unsigned long long)b2) - 1;
        u64 mm = shfl64(m2, ww);
        int bb = __ffsll((unsigned long long)~mm) - 1;
        pj1 = (ww << 6) + bb;
        if (lane == ww) m2 |= (1ull << bb);
        u64 b3 = __ballot((~m2) != 0ull);
        if (b3) {
          int ww2 = __ffsll((unsigned long long)b3) - 1;
          u64 mm2 = shfl64(m2, ww2);
          int bb2 = __ffsll((unsigned long long)~mm2) - 1;
          pj2 = (ww2 << 6) + bb2;
        }
      }
      if (pj1 >= 0) pr1 = (lane < 47) ? mrow[(size_t)pj1 * MWORDS + lane] : 0ull;
      if (pj2 >= 0) pr2 = (lane < 47) ? mrow[(size_t)pj2 * MWORDS + lane] : 0ull;
    }

    remv |= row;        // vmcnt wait lands here, overlapped with prefetch issue
    nexti = i + 1;
  }

  __syncthreads();
  // emit first nk kept in score order, zero-pad to 300
  float4* outv = (float4*)out;
  for (int t = lane; t < POST_NMS; t += 64) {
    float4 v = make_float4(0.f, 0.f, 0.f, 0.f);
    if (t < nk) v = boxes_ws[b * PRE_NMS + s_kept[t]];
    outv[b * POST_NMS + t] = v;
  }
}

// ---------------------------------------------------------------------------
// Fallback: round-1 monolithic kernel (verified) if ws is too small.
// ---------------------------------------------------------------------------
__global__ void __launch_bounds__(NTH)
rpn_proposal_mono(const float* __restrict__ scores,
                  const float* __restrict__ deltas,
                  float* __restrict__ out)
{
  __shared__ __align__(16) char smem[16384 + 32768 + 4096];
  u32* s_hist = (u32*)smem;
  u64* s_cand = (u64*)(smem + 16384);
  u32* s_sfx  = (u32*)(smem + 16384 + 32768);
  float4* s_box = (float4*)smem;
  __shared__ u32 s_kept[POST_NMS];
  __shared__ u32 s_meta[4];

  const int tid = threadIdx.x;
  const int b   = blockIdx.x;
  const float* sc = scores + b * NBOX;

  for (int t = tid; t < NBUCKET; t += NTH) s_hist[t] = 0;
  if (tid < 4) s_meta[tid] = 0;
  __syncthreads();
  for (int m = 0; m < PER; ++m) {
    int i = tid + m * NTH;
    if (i < NBOX) {
      float s = sc[i];
      int bk = (int)(s * (float)NBUCKET);
      bk = bk < 0 ? 0 : (bk > NBUCKET - 1 ? NBUCKET - 1 : bk);
      atomicAdd(&s_hist[bk], 1u);
    }
  }
  __syncthreads();
  {
    u32 g = s_hist[4*tid] + s_hist[4*tid+1] + s_hist[4*tid+2] + s_hist[4*tid+3];
    s_sfx[tid] = g;
  }
  __syncthreads();
  for (int d = 1; d < NTH; d <<= 1) {
    u32 v = (tid + d < NTH) ? s_sfx[tid + d] : 0u;
    __syncthreads();
    s_sfx[tid] += v;
    __syncthreads();
  }
  {
    u32 sg  = s_sfx[tid];
    u32 sgn = (tid < NTH - 1) ? s_sfx[tid + 1] : 0u;
    if (sg >= PRE_NMS && sgn < PRE_NMS) {
      u32 c = sgn;
      for (int t = 4 * tid + 3; t >= 4 * tid; --t) {
        c += s_hist[t];
        if (c >= PRE_NMS) { s_meta[0] = (u32)t; s_meta[1] = c; break; }
      }
    }
  }
  __syncthreads();
  const u32 T = s_meta[0];
  for (int m = 0; m < PER; ++m) {
    int i = tid + m * NTH;
    if (i < NBOX) {
      float s = sc[i];
      int bk = (int)(s * (float)NBUCKET);
      bk = bk < 0 ? 0 : (bk > NBUCKET - 1 ? NBUCKET - 1 : bk);
      if ((u32)bk >= T) {
        u32 pos = atomicAdd(&s_meta[2], 1u);
        if (pos < CAP) {
          u64 key = ((u64)__float_as_uint(s) << 32) | (u32)(~(u32)i);
          s_cand[pos] = key;
        }
      }
    }
  }
  __syncthreads();
  {
    u32 C = s_meta[2]; if (C > CAP) C = CAP;
    for (u32 p = C + tid; p < CAP; p += NTH) s_cand[p] = 0ull;
  }
  for (int kk = 2; kk <= CAP; kk <<= 1) {
    for (int j = kk >> 1; j > 0; j >>= 1) {
      __syncthreads();
      #pragma unroll
      for (int m = 0; m < 2; ++m) {
        int t = tid + m * NTH;
        int i = ((t & ~(j - 1)) << 1) | (t & (j - 1));
        int p = i | j;
        u64 a  = s_cand[i];
        u64 bb = s_cand[p];
        bool desc = (i & kk) == 0;
        bool sw = desc ? (a < bb) : (a > bb);
        if (sw) { s_cand[i] = bb; s_cand[p] = a; }
      }
    }
  }
  __syncthreads();
  const float* dl = deltas + b * (4 * NA * HW);
  float4 bx[3];
  #pragma unroll
  for (int m = 0; m < 3; ++m) {
    int k = tid + m * NTH;
    if (k < PRE_NMS) {
      u64 key = s_cand[k];
      int idx = (int)(~(u32)key);
      int a = idx / HW;
      int r = idx - a * HW;
      int h = r / NW;
      int w = r - h * NW;
      const float* dp = dl + (4 * a) * HW + r;
      float tx = dp[0];
      float ty = dp[HW];
      float tw = dp[2 * HW];
      float th = dp[3 * HW];
      float aw = c_aw[a], ah = c_ah[a];
      float ctr_x = ((float)w + 0.5f) * 16.0f + tx * aw;
      float ctr_y = ((float)h + 0.5f) * 16.0f + ty * ah;
      float w1 = expf(tw) * aw;
      float h1 = expf(th) * ah;
      float x1 = ctr_x - 0.5f * w1;
      float y1 = ctr_y - 0.5f * h1;
      float x2 = x1 + w1;
      float y2 = y1 + h1;
      x1 = fminf(fmaxf(x1, 0.0f), 959.0f);
      x2 = fminf(fmaxf(x2, 0.0f), 959.0f);
      y1 = fminf(fmaxf(y1, 0.0f), 543.0f);
      y2 = fminf(fmaxf(y2, 0.0f), 543.0f);
      bx[m] = make_float4(x1, y1, x2, y2);
    }
  }
  __syncthreads();
  #pragma unroll
  for (int m = 0; m < 3; ++m) {
    int k = tid + m * NTH;
    if (k < PRE_NMS) s_box[k] = bx[m];
  }
  __syncthreads();
  if (tid < 64) {
    const int lane = tid;
    float4 kb[5];
    float  ka[5];
    int nk = 0;
    for (int i = 0; i < PRE_NMS; ++i) {
      if (nk >= POST_NMS) break;
      float4 c = s_box[i];
      float carea = (c.z - c.x) * (c.w - c.y);
      bool over = false;
      #pragma unroll
      for (int s = 0; s < 5; ++s) {
        if (s * 64 < nk) {
          if (s * 64 + lane < nk) {
            float iw = fminf(kb[s].z, c.z) - fmaxf(kb[s].x, c.x);
            float ih = fminf(kb[s].w, c.w) - fmaxf(kb[s].y, c.y);
            iw = fmaxf(iw, 0.0f);
            ih = fmaxf(ih, 0.0f);
            float inter = iw * ih;
            float uni = ka[s] + carea - inter;
            over = over || (inter > 0.7f * fmaxf(uni, 1e-8f));
          }
        }
      }
      if (__ballot((int)over) == 0ull) {
        int s = nk >> 6, l = nk & 63;
        #pragma unroll
        for (int q = 0; q < 5; ++q)
          if (q == s && lane == l) { kb[q] = c; ka[q] = carea; }
        if (lane == 0) s_kept[nk] = (u32)i;
        ++nk;
      }
    }
    if (lane == 0) s_meta[3] = (u32)nk;
  }
  __syncthreads();
  if (tid < POST_NMS) {
    u32 nk = s_meta[3];
    float4 v = make_float4(0.0f, 0.0f, 0.0f, 0.0f);
    if ((u32)tid < nk) v = s_box[s_kept[tid]];
    ((float4*)out)[b * POST_NMS + tid] = v;
  }
}

extern "C" void kernel_launch(void* const* d_in, const int* in_sizes, int n_in,
                              void* d_out, int out_size, void* d_ws, size_t ws_size,
                              hipStream_t stream) {
  const float* scores = (const float*)d_in[0];
  const float* deltas = (const float*)d_in[1];
  (void)in_sizes; (void)n_in; (void)out_size;

  const size_t boxes_bytes = (size_t)NB * PRE_NMS * sizeof(float4);   // 192000
  const size_t mask_off    = 196608;                                  // 192KB aligned
  const size_t mask_bytes  = (size_t)NB * PRE_NMS * MWORDS * sizeof(u64); // 4608000
  const size_t need        = mask_off + mask_bytes;

  if (ws_size >= need) {
    float4* boxes_ws = (float4*)d_ws;
    u64*    masks    = (u64*)((char*)d_ws + mask_off);
    topk_sort_decode_kernel<<<dim3(NB), dim3(NTH), 0, stream>>>(scores, deltas, boxes_ws);
    mask_kernel<<<dim3(47, 12, NB), dim3(256), 0, stream>>>(boxes_ws, masks);
    nms_reduce_kernel<<<dim3(NB), dim3(64), 0, stream>>>(boxes_ws, masks, (float*)d_out);
    (void)boxes_bytes;
  } else {
    rpn_proposal_mono<<<dim3(NB), dim3(NTH), 0, stream>>>(scores, deltas, (float*)d_out);
  }
}

// Round 3
// 228.459 us; speedup vs baseline: 1.5854x; 1.5854x over previous
//
#include <hip/hip_runtime.h>
#include <stdint.h>

typedef uint32_t u32;
typedef uint64_t u64;

#define NB 4
#define NA 9
#define NH 34
#define NW 60
#define HW (NH*NW)            // 2040
#define NBOX (NA*HW)          // 18360
#define PRE_NMS 3000
#define POST_NMS 300
#define NBUCKET 4096
#define CAP 4096
#define NTH 1024
#define PER 18                // 18*1024 = 18432 >= 18360
#define MWORDS 48             // 48*64 = 3072 >= 3000 candidate bits per mask row
#define WDEPTH 8              // speculative prefetch window (rows in flight)

// Anchor widths/heights (f64->f32 roundings, matching np.array(..., float32)).
__device__ __constant__ float c_aw[9] = {
  45.254833995939045f, 64.0f,  90.50966799187808f,
  90.50966799187808f,  128.0f, 181.01933598375617f,
  181.01933598375617f, 256.0f, 362.03867196751233f };
__device__ __constant__ float c_ah[9] = {
  90.50966799187808f,  64.0f,  45.254833995939045f,
  181.01933598375617f, 128.0f, 90.50966799187808f,
  362.03867196751233f, 256.0f, 181.01933598375617f };

__device__ __forceinline__ u64 readlane64(u64 v, int lane) {
  u32 lo = __builtin_amdgcn_readlane((u32)(v & 0xffffffffull), lane);
  u32 hi = __builtin_amdgcn_readlane((u32)(v >> 32), lane);
  return ((u64)hi << 32) | lo;
}

// ---------------------------------------------------------------------------
// K1: histogram top-3000 select + bitonic sort + decode -> ws boxes
// ---------------------------------------------------------------------------
__global__ void __launch_bounds__(NTH)
topk_sort_decode_kernel(const float* __restrict__ scores,
                        const float* __restrict__ deltas,
                        float4* __restrict__ boxes_ws)
{
  __shared__ __align__(16) char smem[16384 + 32768 + 4096];
  u32* s_hist = (u32*)smem;
  u64* s_cand = (u64*)(smem + 16384);
  u32* s_sfx  = (u32*)(smem + 16384 + 32768);
  __shared__ u32 s_meta[4];

  const int tid = threadIdx.x;
  const int b   = blockIdx.x;
  const float* sc = scores + b * NBOX;

  for (int t = tid; t < NBUCKET; t += NTH) s_hist[t] = 0;
  if (tid < 4) s_meta[tid] = 0;
  __syncthreads();

  // histogram
  for (int m = 0; m < PER; ++m) {
    int i = tid + m * NTH;
    if (i < NBOX) {
      float s = sc[i];
      int bk = (int)(s * (float)NBUCKET);
      bk = bk < 0 ? 0 : (bk > NBUCKET - 1 ? NBUCKET - 1 : bk);
      atomicAdd(&s_hist[bk], 1u);
    }
  }
  __syncthreads();

  // 4-bucket group sums + inclusive suffix scan over 1024 groups
  {
    u32 g = s_hist[4*tid] + s_hist[4*tid+1] + s_hist[4*tid+2] + s_hist[4*tid+3];
    s_sfx[tid] = g;
  }
  __syncthreads();
  for (int d = 1; d < NTH; d <<= 1) {
    u32 v = (tid + d < NTH) ? s_sfx[tid + d] : 0u;
    __syncthreads();
    s_sfx[tid] += v;
    __syncthreads();
  }

  // threshold bucket T
  {
    u32 sg  = s_sfx[tid];
    u32 sgn = (tid < NTH - 1) ? s_sfx[tid + 1] : 0u;
    if (sg >= PRE_NMS && sgn < PRE_NMS) {
      u32 c = sgn;
      for (int t = 4 * tid + 3; t >= 4 * tid; --t) {
        c += s_hist[t];
        if (c >= PRE_NMS) { s_meta[0] = (u32)t; s_meta[1] = c; break; }
      }
    }
  }
  __syncthreads();
  const u32 T = s_meta[0];

  // compact candidates
  for (int m = 0; m < PER; ++m) {
    int i = tid + m * NTH;
    if (i < NBOX) {
      float s = sc[i];
      int bk = (int)(s * (float)NBUCKET);
      bk = bk < 0 ? 0 : (bk > NBUCKET - 1 ? NBUCKET - 1 : bk);
      if ((u32)bk >= T) {
        u32 pos = atomicAdd(&s_meta[2], 1u);
        if (pos < CAP) {
          u64 key = ((u64)__float_as_uint(s) << 32) | (u32)(~(u32)i);
          s_cand[pos] = key;
        }
      }
    }
  }
  __syncthreads();
  {
    u32 C = s_meta[2]; if (C > CAP) C = CAP;
    for (u32 p = C + tid; p < CAP; p += NTH) s_cand[p] = 0ull;
  }

  // bitonic sort 4096 u64, descending
  for (int kk = 2; kk <= CAP; kk <<= 1) {
    for (int j = kk >> 1; j > 0; j >>= 1) {
      __syncthreads();
      #pragma unroll
      for (int m = 0; m < 2; ++m) {
        int t = tid + m * NTH;
        int i = ((t & ~(j - 1)) << 1) | (t & (j - 1));
        int p = i | j;
        u64 a  = s_cand[i];
        u64 bb = s_cand[p];
        bool desc = (i & kk) == 0;
        bool sw = desc ? (a < bb) : (a > bb);
        if (sw) { s_cand[i] = bb; s_cand[p] = a; }
      }
    }
  }
  __syncthreads();

  // decode top-3000 -> ws
  const float* dl = deltas + b * (4 * NA * HW);
  #pragma unroll
  for (int m = 0; m < 3; ++m) {
    int k = tid + m * NTH;
    if (k < PRE_NMS) {
      u64 key = s_cand[k];
      int idx = (int)(~(u32)key);
      int a = idx / HW;
      int r = idx - a * HW;
      int h = r / NW;
      int w = r - h * NW;
      const float* dp = dl + (4 * a) * HW + r;
      float tx = dp[0];
      float ty = dp[HW];
      float tw = dp[2 * HW];
      float th = dp[3 * HW];
      float aw = c_aw[a], ah = c_ah[a];
      float ctr_x = ((float)w + 0.5f) * 16.0f + tx * aw;
      float ctr_y = ((float)h + 0.5f) * 16.0f + ty * ah;
      float w1 = expf(tw) * aw;
      float h1 = expf(th) * ah;
      float x1 = ctr_x - 0.5f * w1;
      float y1 = ctr_y - 0.5f * h1;
      float x2 = x1 + w1;
      float y2 = y1 + h1;
      x1 = fminf(fmaxf(x1, 0.0f), 959.0f);
      x2 = fminf(fmaxf(x2, 0.0f), 959.0f);
      y1 = fminf(fmaxf(y1, 0.0f), 543.0f);
      y2 = fminf(fmaxf(y2, 0.0f), 543.0f);
      boxes_ws[b * PRE_NMS + k] = make_float4(x1, y1, x2, y2);
    }
  }
}

// ---------------------------------------------------------------------------
// K2: suppression bit-matrix. mask[b][i][c] bit k = IoU(box i, box 64c+k)>0.7
// ---------------------------------------------------------------------------
__global__ void __launch_bounds__(256)
mask_kernel(const float4* __restrict__ boxes_ws, u64* __restrict__ masks)
{
  const int b = blockIdx.z, c = blockIdx.x;
  const int tid = threadIdx.x;
  __shared__ float4 s_cb[64];
  __shared__ float  s_ca[64];
  if (tid < 64) {
    int j = c * 64 + tid;
    float4 v = (j < PRE_NMS) ? boxes_ws[b * PRE_NMS + j]
                             : make_float4(0.f, 0.f, 0.f, 0.f);
    s_cb[tid] = v;
    s_ca[tid] = (v.z - v.x) * (v.w - v.y);
  }
  __syncthreads();
  int row = blockIdx.y * 250 + tid;
  if (tid < 250 && row < PRE_NMS) {
    float4 r = boxes_ws[b * PRE_NMS + row];
    float ra = (r.z - r.x) * (r.w - r.y);
    u64 word = 0;
    #pragma unroll
    for (int k = 0; k < 64; ++k) {
      float4 cb = s_cb[k];
      float iw = fminf(r.z, cb.z) - fmaxf(r.x, cb.x);
      float ih = fminf(r.w, cb.w) - fmaxf(r.y, cb.y);
      iw = fmaxf(iw, 0.0f);
      ih = fmaxf(ih, 0.0f);
      float inter = iw * ih;
      float uni = ra + s_ca[k] - inter;
      word |= ((u64)(inter > 0.7f * fmaxf(uni, 1e-8f))) << k;
    }
    masks[((size_t)b * PRE_NMS + row) * MWORDS + c] = word;
  }
}

// ---------------------------------------------------------------------------
// K3 v2: serial greedy reduce with a depth-8 speculative row window.
// Lane w owns removed-bitmap word w (registers). Window = next 8 clear
// candidate indices, their mask rows in flight in 8 static register slots
// (loop unrolled x8 -> per-slot vmcnt). Exactly one unconditional row load
// per pop keeps the vmcnt FIFO statically trackable. All cross-lane traffic
// is v_readlane (wave-uniform index) - no ds_bpermute on the chain.
// Pops occur in ascending candidate order and every entry is re-validated
// against the fully-updated removed bitmap at pop time => exact greedy NMS.
// ---------------------------------------------------------------------------
__global__ void __launch_bounds__(64)
nms_reduce_kernel(const float4* __restrict__ boxes_ws,
                  const u64* __restrict__ masks,
                  float* __restrict__ out)
{
  const int b = blockIdx.x;
  const int lane = threadIdx.x;
  __shared__ u32 s_kept[POST_NMS];
  __shared__ u32 s_nk;

  // removed bitmap: lane w owns bits [64w, 64w+64). Pre-set bits >= 3000.
  u64 removed;
  if (lane < 46)       removed = 0ull;
  else if (lane == 46) removed = ~((1ull << 56) - 1);   // bits 3000..3007
  else                 removed = ~0ull;                 // lanes 47..63

  const u64* mrow = masks + (size_t)b * PRE_NMS * MWORDS;

  int idx[WDEPTH];
  u64 r[WDEPTH];
  #pragma unroll
  for (int s = 0; s < WDEPTH; ++s) {
    idx[s] = s;                                   // bits 0..7 clear initially
    r[s] = (lane < 47) ? mrow[(size_t)s * MWORDS + lane] : 0ull;
  }
  int tail = WDEPTH;
  int nk = 0;
  bool done = false;

  while (!done) {
    #pragma unroll
    for (int s = 0; s < WDEPTH; ++s) {
      int i = idx[s];
      bool alive = !done;
      if (alive && i < 0) { done = true; alive = false; }   // window exhausted
      if (alive) {
        // re-validate window head against current removed bitmap
        int iw_ = i >> 6, ib = i & 63;
        u64 wv = readlane64(removed, iw_);
        if (!((wv >> ib) & 1ull)) {               // still clear -> kept
          if (lane == 0) s_kept[nk] = (u32)i;
          removed |= r[s];                        // one v_or per lane
          ++nk;
          if (nk >= POST_NMS) done = true;
        }
      }
      // refill slot s: next clear bit >= tail (post-OR removed)
      int j = -1;
      if (alive && !done) {
        u64 m = removed;
        int tw = tail >> 6, tb = tail & 63;
        if (lane < tw) m = ~0ull;
        else if (lane == tw && tb) m |= ((1ull << tb) - 1ull);
        u64 bal = __ballot((~m) != 0ull);
        if (bal != 0ull) {
          int w0 = __ffsll((unsigned long long)bal) - 1;
          u64 mw = readlane64(m, w0);
          j = (w0 << 6) + (__ffsll((unsigned long long)(~mw)) - 1);
          tail = j + 1;
        }
      }
      idx[s] = j;
      int js = j < 0 ? 0 : j;
      // unconditional load: consumed WDEPTH-1 pops later (latency hidden)
      r[s] = (lane < 47) ? mrow[(size_t)js * MWORDS + lane] : 0ull;
    }
  }
  if (lane == 0) s_nk = (u32)nk;
  __syncthreads();

  // emit first nk kept in score order, zero-pad to 300
  float4* outv = (float4*)out;
  u32 fnk = s_nk;
  for (int t = lane; t < POST_NMS; t += 64) {
    float4 v = make_float4(0.f, 0.f, 0.f, 0.f);
    if ((u32)t < fnk) v = boxes_ws[b * PRE_NMS + s_kept[t]];
    outv[b * POST_NMS + t] = v;
  }
}

// ---------------------------------------------------------------------------
// Fallback: round-1 monolithic kernel (verified) if ws is too small.
// ---------------------------------------------------------------------------
__global__ void __launch_bounds__(NTH)
rpn_proposal_mono(const float* __restrict__ scores,
                  const float* __restrict__ deltas,
                  float* __restrict__ out)
{
  __shared__ __align__(16) char smem[16384 + 32768 + 4096];
  u32* s_hist = (u32*)smem;
  u64* s_cand = (u64*)(smem + 16384);
  u32* s_sfx  = (u32*)(smem + 16384 + 32768);
  float4* s_box = (float4*)smem;
  __shared__ u32 s_kept[POST_NMS];
  __shared__ u32 s_meta[4];

  const int tid = threadIdx.x;
  const int b   = blockIdx.x;
  const float* sc = scores + b * NBOX;

  for (int t = tid; t < NBUCKET; t += NTH) s_hist[t] = 0;
  if (tid < 4) s_meta[tid] = 0;
  __syncthreads();
  for (int m = 0; m < PER; ++m) {
    int i = tid + m * NTH;
    if (i < NBOX) {
      float s = sc[i];
      int bk = (int)(s * (float)NBUCKET);
      bk = bk < 0 ? 0 : (bk > NBUCKET - 1 ? NBUCKET - 1 : bk);
      atomicAdd(&s_hist[bk], 1u);
    }
  }
  __syncthreads();
  {
    u32 g = s_hist[4*tid] + s_hist[4*tid+1] + s_hist[4*tid+2] + s_hist[4*tid+3];
    s_sfx[tid] = g;
  }
  __syncthreads();
  for (int d = 1; d < NTH; d <<= 1) {
    u32 v = (tid + d < NTH) ? s_sfx[tid + d] : 0u;
    __syncthreads();
    s_sfx[tid] += v;
    __syncthreads();
  }
  {
    u32 sg  = s_sfx[tid];
    u32 sgn = (tid < NTH - 1) ? s_sfx[tid + 1] : 0u;
    if (sg >= PRE_NMS && sgn < PRE_NMS) {
      u32 c = sgn;
      for (int t = 4 * tid + 3; t >= 4 * tid; --t) {
        c += s_hist[t];
        if (c >= PRE_NMS) { s_meta[0] = (u32)t; s_meta[1] = c; break; }
      }
    }
  }
  __syncthreads();
  const u32 T = s_meta[0];
  for (int m = 0; m < PER; ++m) {
    int i = tid + m * NTH;
    if (i < NBOX) {
      float s = sc[i];
      int bk = (int)(s * (float)NBUCKET);
      bk = bk < 0 ? 0 : (bk > NBUCKET - 1 ? NBUCKET - 1 : bk);
      if ((u32)bk >= T) {
        u32 pos = atomicAdd(&s_meta[2], 1u);
        if (pos < CAP) {
          u64 key = ((u64)__float_as_uint(s) << 32) | (u32)(~(u32)i);
          s_cand[pos] = key;
        }
      }
    }
  }
  __syncthreads();
  {
    u32 C = s_meta[2]; if (C > CAP) C = CAP;
    for (u32 p = C + tid; p < CAP; p += NTH) s_cand[p] = 0ull;
  }
  for (int kk = 2; kk <= CAP; kk <<= 1) {
    for (int j = kk >> 1; j > 0; j >>= 1) {
      __syncthreads();
      #pragma unroll
      for (int m = 0; m < 2; ++m) {
        int t = tid + m * NTH;
        int i = ((t & ~(j - 1)) << 1) | (t & (j - 1));
        int p = i | j;
        u64 a  = s_cand[i];
        u64 bb = s_cand[p];
        bool desc = (i & kk) == 0;
        bool sw = desc ? (a < bb) : (a > bb);
        if (sw) { s_cand[i] = bb; s_cand[p] = a; }
      }
    }
  }
  __syncthreads();
  const float* dl = deltas + b * (4 * NA * HW);
  float4 bx[3];
  #pragma unroll
  for (int m = 0; m < 3; ++m) {
    int k = tid + m * NTH;
    if (k < PRE_NMS) {
      u64 key = s_cand[k];
      int idx = (int)(~(u32)key);
      int a = idx / HW;
      int r = idx - a * HW;
      int h = r / NW;
      int w = r - h * NW;
      const float* dp = dl + (4 * a) * HW + r;
      float tx = dp[0];
      float ty = dp[HW];
      float tw = dp[2 * HW];
      float th = dp[3 * HW];
      float aw = c_aw[a], ah = c_ah[a];
      float ctr_x = ((float)w + 0.5f) * 16.0f + tx * aw;
      float ctr_y = ((float)h + 0.5f) * 16.0f + ty * ah;
      float w1 = expf(tw) * aw;
      float h1 = expf(th) * ah;
      float x1 = ctr_x - 0.5f * w1;
      float y1 = ctr_y - 0.5f * h1;
      float x2 = x1 + w1;
      float y2 = y1 + h1;
      x1 = fminf(fmaxf(x1, 0.0f), 959.0f);
      x2 = fminf(fmaxf(x2, 0.0f), 959.0f);
      y1 = fminf(fmaxf(y1, 0.0f), 543.0f);
      y2 = fminf(fmaxf(y2, 0.0f), 543.0f);
      bx[m] = make_float4(x1, y1, x2, y2);
    }
  }
  __syncthreads();
  #pragma unroll
  for (int m = 0; m < 3; ++m) {
    int k = tid + m * NTH;
    if (k < PRE_NMS) s_box[k] = bx[m];
  }
  __syncthreads();
  if (tid < 64) {
    const int lane = tid;
    float4 kb[5];
    float  ka[5];
    int nk = 0;
    for (int i = 0; i < PRE_NMS; ++i) {
      if (nk >= POST_NMS) break;
      float4 c = s_box[i];
      float carea = (c.z - c.x) * (c.w - c.y);
      bool over = false;
      #pragma unroll
      for (int s = 0; s < 5; ++s) {
        if (s * 64 < nk) {
          if (s * 64 + lane < nk) {
            float iw = fminf(kb[s].z, c.z) - fmaxf(kb[s].x, c.x);
            float ih = fminf(kb[s].w, c.w) - fmaxf(kb[s].y, c.y);
            iw = fmaxf(iw, 0.0f);
            ih = fmaxf(ih, 0.0f);
            float inter = iw * ih;
            float uni = ka[s] + carea - inter;
            over = over || (inter > 0.7f * fmaxf(uni, 1e-8f));
          }
        }
      }
      if (__ballot((int)over) == 0ull) {
        int s = nk >> 6, l = nk & 63;
        #pragma unroll
        for (int q = 0; q < 5; ++q)
          if (q == s && lane == l) { kb[q] = c; ka[q] = carea; }
        if (lane == 0) s_kept[nk] = (u32)i;
        ++nk;
      }
    }
    if (lane == 0) s_meta[3] = (u32)nk;
  }
  __syncthreads();
  if (tid < POST_NMS) {
    u32 nk = s_meta[3];
    float4 v = make_float4(0.0f, 0.0f, 0.0f, 0.0f);
    if ((u32)tid < nk) v = s_box[s_kept[tid]];
    ((float4*)out)[b * POST_NMS + tid] = v;
  }
}

extern "C" void kernel_launch(void* const* d_in, const int* in_sizes, int n_in,
                              void* d_out, int out_size, void* d_ws, size_t ws_size,
                              hipStream_t stream) {
  const float* scores = (const float*)d_in[0];
  const float* deltas = (const float*)d_in[1];
  (void)in_sizes; (void)n_in; (void)out_size;

  const size_t mask_off   = 196608;                                      // 192KB aligned
  const size_t mask_bytes = (size_t)NB * PRE_NMS * MWORDS * sizeof(u64); // 4.6MB
  const size_t need       = mask_off + mask_bytes;

  if (ws_size >= need) {
    float4* boxes_ws = (float4*)d_ws;
    u64*    masks    = (u64*)((char*)d_ws + mask_off);
    topk_sort_decode_kernel<<<dim3(NB), dim3(NTH), 0, stream>>>(scores, deltas, boxes_ws);
    mask_kernel<<<dim3(47, 12, NB), dim3(256), 0, stream>>>(boxes_ws, masks);
    nms_reduce_kernel<<<dim3(NB), dim3(64), 0, stream>>>(boxes_ws, masks, (float*)d_out);
  } else {
    rpn_proposal_mono<<<dim3(NB), dim3(NTH), 0, stream>>>(scores, deltas, (float*)d_out);
  }
}

// Round 4
// 216.995 us; speedup vs baseline: 1.6691x; 1.0528x over previous
//
#include <hip/hip_runtime.h>
#include <stdint.h>

typedef uint32_t u32;
typedef uint64_t u64;

#define NB 4
#define NA 9
#define NH 34
#define NW 60
#define HW (NH*NW)            // 2040
#define NBOX (NA*HW)          // 18360
#define PRE_NMS 3000
#define POST_NMS 300
#define NBUCKET 4096
#define SEGCAP 4096
#define NTH 1024
#define PER 18                // 18*1024 = 18432 >= 18360
#define MWORDS 48             // 48*64 = 3072 >= 3000 candidate bits per mask row
#define WIN 8                 // kept-batch width in the NMS reduce

// Anchor widths/heights (f64->f32 roundings, matching np.array(..., float32)).
__device__ __constant__ float c_aw[9] = {
  45.254833995939045f, 64.0f,  90.50966799187808f,
  90.50966799187808f,  128.0f, 181.01933598375617f,
  181.01933598375617f, 256.0f, 362.03867196751233f };
__device__ __constant__ float c_ah[9] = {
  90.50966799187808f,  64.0f,  45.254833995939045f,
  181.01933598375617f, 128.0f, 90.50966799187808f,
  362.03867196751233f, 256.0f, 181.01933598375617f };

__device__ __forceinline__ u64 readlane64(u64 v, int lane) {
  u32 lo = __builtin_amdgcn_readlane((u32)(v & 0xffffffffull), lane);
  u32 hi = __builtin_amdgcn_readlane((u32)(v >> 32), lane);
  return ((u64)hi << 32) | lo;
}

__device__ __forceinline__ float4 decode_box(const float* __restrict__ dl, int idx) {
  int a = idx / HW;
  int r = idx - a * HW;
  int h = r / NW;
  int w = r - h * NW;
  const float* dp = dl + (4 * a) * HW + r;
  float tx = dp[0];
  float ty = dp[HW];
  float tw = dp[2 * HW];
  float th = dp[3 * HW];
  float aw = c_aw[a], ah = c_ah[a];
  float ctr_x = ((float)w + 0.5f) * 16.0f + tx * aw;
  float ctr_y = ((float)h + 0.5f) * 16.0f + ty * ah;
  float w1 = expf(tw) * aw;
  float h1 = expf(th) * ah;
  float x1 = ctr_x - 0.5f * w1;
  float y1 = ctr_y - 0.5f * h1;
  float x2 = x1 + w1;
  float y2 = y1 + h1;
  x1 = fminf(fmaxf(x1, 0.0f), 959.0f);
  x2 = fminf(fmaxf(x2, 0.0f), 959.0f);
  y1 = fminf(fmaxf(y1, 0.0f), 543.0f);
  y2 = fminf(fmaxf(y2, 0.0f), 543.0f);
  return make_float4(x1, y1, x2, y2);
}

// ---------------------------------------------------------------------------
// K1 v2: sort-free exact ranking.
// rank(c) = (#elems in higher buckets) + (#same-bucket peers with larger key).
// Keys (scorebits<<32 | ~idx) are unique => ranks exact, match lax.top_k's
// (score desc, idx asc) order. Only buckets with base<3000 are materialized.
// ---------------------------------------------------------------------------
__global__ void __launch_bounds__(NTH)
topk_rank_decode_kernel(const float* __restrict__ scores,
                        const float* __restrict__ deltas,
                        float4* __restrict__ boxes_ws)
{
  __shared__ u32 s_base[NBUCKET];   // #elements in buckets > t
  __shared__ u32 s_cnt[NBUCKET];    // hist, then segment fill counters
  __shared__ u64 s_keys[SEGCAP];    // bucket-segmented candidate keys
  __shared__ u32 s_sfx[NTH];        // group suffix sums

  const int tid = threadIdx.x;
  const int b   = blockIdx.x;
  const float* sc = scores + b * NBOX;

  for (int t = tid; t < NBUCKET; t += NTH) s_cnt[t] = 0;
  __syncthreads();

  // histogram
  for (int m = 0; m < PER; ++m) {
    int i = tid + m * NTH;
    if (i < NBOX) {
      float s = sc[i];
      int bk = (int)(s * (float)NBUCKET);
      bk = bk < 0 ? 0 : (bk > NBUCKET - 1 ? NBUCKET - 1 : bk);
      atomicAdd(&s_cnt[bk], 1u);
    }
  }
  __syncthreads();

  // group-of-4 sums + inclusive suffix scan over 1024 groups
  u32 h0 = s_cnt[4*tid], h1 = s_cnt[4*tid+1], h2 = s_cnt[4*tid+2], h3 = s_cnt[4*tid+3];
  s_sfx[tid] = h0 + h1 + h2 + h3;
  __syncthreads();
  for (int d = 1; d < NTH; d <<= 1) {
    u32 v = (tid + d < NTH) ? s_sfx[tid + d] : 0u;
    __syncthreads();
    s_sfx[tid] += v;
    __syncthreads();
  }

  // per-bucket base = #elements in strictly higher buckets
  {
    u32 Gn = (tid < NTH - 1) ? s_sfx[tid + 1] : 0u;
    s_base[4*tid+3] = Gn;
    s_base[4*tid+2] = Gn + h3;
    s_base[4*tid+1] = Gn + h3 + h2;
    s_base[4*tid+0] = Gn + h3 + h2 + h1;
  }
  __syncthreads();

  // reset counters, zero key slots (key 0 decodes to bucket 0 -> discarded)
  for (int t = tid; t < NBUCKET; t += NTH) s_cnt[t] = 0;
  for (int t = tid; t < SEGCAP; t += NTH) s_keys[t] = 0ull;
  __syncthreads();

  // scatter candidates of buckets with base < 3000 into their segment
  for (int m = 0; m < PER; ++m) {
    int i = tid + m * NTH;
    if (i < NBOX) {
      float s = sc[i];
      int bk = (int)(s * (float)NBUCKET);
      bk = bk < 0 ? 0 : (bk > NBUCKET - 1 ? NBUCKET - 1 : bk);
      u32 base = s_base[bk];
      if (base < PRE_NMS) {
        u32 loc = atomicAdd(&s_cnt[bk], 1u);
        u32 pos = base + loc;
        if (pos < SEGCAP) {
          u64 key = ((u64)__float_as_uint(s) << 32) | (u32)(~(u32)i);
          s_keys[pos] = key;
        }
      }
    }
  }
  __syncthreads();

  // exact rank via bucket-peer scan; decode winners straight to rank slot
  const float* dl = deltas + b * (4 * NA * HW);
  for (int m = 0; m < SEGCAP / NTH; ++m) {
    int p = tid + m * NTH;
    u64 key = s_keys[p];
    float s = __uint_as_float((u32)(key >> 32));
    int bk = (int)(s * (float)NBUCKET);
    bk = bk < 0 ? 0 : (bk > NBUCKET - 1 ? NBUCKET - 1 : bk);
    u32 base = s_base[bk];
    u32 cnt  = s_cnt[bk];
    u32 local = 0;
    for (u32 q = base; q < base + cnt; ++q)
      local += (s_keys[q] > key) ? 1u : 0u;
    u32 R = base + local;
    if (key != 0ull && R < PRE_NMS) {
      int idx = (int)(~(u32)key);
      boxes_ws[b * PRE_NMS + R] = decode_box(dl, idx);
    }
  }
}

// ---------------------------------------------------------------------------
// K2: suppression bit-matrix. mask[b][i][c] bit k = IoU(box i, box 64c+k)>0.7
// ---------------------------------------------------------------------------
__global__ void __launch_bounds__(256)
mask_kernel(const float4* __restrict__ boxes_ws, u64* __restrict__ masks)
{
  const int b = blockIdx.z, c = blockIdx.x;
  const int tid = threadIdx.x;
  __shared__ float4 s_cb[64];
  __shared__ float  s_ca[64];
  if (tid < 64) {
    int j = c * 64 + tid;
    float4 v = (j < PRE_NMS) ? boxes_ws[b * PRE_NMS + j]
                             : make_float4(0.f, 0.f, 0.f, 0.f);
    s_cb[tid] = v;
    s_ca[tid] = (v.z - v.x) * (v.w - v.y);
  }
  __syncthreads();
  int row = blockIdx.y * 250 + tid;
  if (tid < 250 && row < PRE_NMS) {
    float4 r = boxes_ws[b * PRE_NMS + row];
    float ra = (r.z - r.x) * (r.w - r.y);
    u64 word = 0;
    #pragma unroll
    for (int k = 0; k < 64; ++k) {
      float4 cb = s_cb[k];
      float iw = fminf(r.z, cb.z) - fmaxf(r.x, cb.x);
      float ih = fminf(r.w, cb.w) - fmaxf(r.y, cb.y);
      iw = fmaxf(iw, 0.0f);
      ih = fmaxf(ih, 0.0f);
      float inter = iw * ih;
      float uni = ra + s_ca[k] - inter;
      word |= ((u64)(inter > 0.7f * fmaxf(uni, 1e-8f))) << k;
    }
    masks[((size_t)b * PRE_NMS + row) * MWORDS + c] = word;
  }
}

// ---------------------------------------------------------------------------
// K3 v3: batched greedy reduce, 8 kept per serial step.
// Lane w owns removed word w. Window of 8 enqueued indices + resident rows.
// Per iteration: (1) speculatively pick next 8 clear bits (pre-OR bitmap),
// (2) issue their 8 row loads, (3) validate current 8 vs removed, (4) 28 pair
// bits from resident rows, (5) SALU keep chain (gated at 300), (6) OR kept
// rows into removed. Entries invalidated between enqueue and validation are
// discarded exactly; suppressed bits never clear => exact greedy NMS.
// ---------------------------------------------------------------------------
__global__ void __launch_bounds__(64)
nms_reduce_kernel(const float4* __restrict__ boxes_ws,
                  const u64* __restrict__ masks,
                  float* __restrict__ out)
{
  const int b = blockIdx.x;
  const int lane = threadIdx.x;
  __shared__ u32 s_kept[POST_NMS];

  // removed bitmap: lane w owns bits [64w, 64w+64). Bits >= 3000 pre-set.
  u64 removed;
  if (lane < 46)       removed = 0ull;
  else if (lane == 46) removed = ~((1ull << 56) - 1);   // bits 3000..3007
  else                 removed = ~0ull;

  const u64* mrow = masks + (size_t)b * PRE_NMS * MWORDS;

  int wi[WIN];
  u64 r[WIN];
  #pragma unroll
  for (int s = 0; s < WIN; ++s) {
    wi[s] = s;                                    // bits 0..7 clear initially
    r[s] = (lane < 47) ? mrow[(size_t)s * MWORDS + lane] : 0ull;
  }
  int tail = WIN;
  int nk = 0;

  for (int iter = 0; iter < 376 && nk < POST_NMS; ++iter) {
    // (1) pick next-window indices from current (pre-OR) bitmap
    int ni[WIN];
    {
      int w = tail >> 6;
      u64 cw = readlane64(removed, w);
      int tb = tail & 63;
      if (tb) cw |= (1ull << tb) - 1ull;
      #pragma unroll
      for (int s = 0; s < WIN; ++s) {
        while (~cw == 0ull && w < 46) { ++w; cw = readlane64(removed, w); }
        if (~cw != 0ull) {
          int bp = __ffsll((unsigned long long)(~cw)) - 1;
          ni[s] = (w << 6) + bp;
          cw |= (1ull << bp);
        } else {
          ni[s] = PRE_NMS;                        // sentinel: bit 3000 pre-set
        }
      }
      tail = ni[WIN - 1] + 1;
      if (tail > PRE_NMS) tail = PRE_NMS;
    }
    // (2) issue next-window row loads (consumed next iteration)
    u64 nr[WIN];
    #pragma unroll
    for (int s = 0; s < WIN; ++s) {
      int js = ni[s] < PRE_NMS ? ni[s] : PRE_NMS - 1;   // clamp; sentinel never kept
      nr[s] = (lane < 47) ? mrow[(size_t)js * MWORDS + lane] : 0ull;
    }
    // (3) validate current window vs removed
    u32 avail = 0;
    #pragma unroll
    for (int s = 0; s < WIN; ++s) {
      u64 wv = readlane64(removed, wi[s] >> 6);
      avail |= (u32)(((~wv) >> (wi[s] & 63)) & 1ull) << s;
    }
    // (4) pair bits: sup[j] bit k = row j suppresses index wi[k] (j<k)
    u32 sup[WIN];
    #pragma unroll
    for (int j = 0; j < WIN; ++j) {
      u32 m = 0;
      #pragma unroll
      for (int k = j + 1; k < WIN; ++k) {
        u64 rv = readlane64(r[j], wi[k] >> 6);
        m |= (u32)((rv >> (wi[k] & 63)) & 1ull) << k;
      }
      sup[j] = m;
    }
    // (5) keep chain (wave-uniform SALU), gated at POST_NMS
    u32 keep = 0;
    #pragma unroll
    for (int k = 0; k < WIN; ++k) {
      bool kb = ((avail >> k) & 1u) && (nk + (int)__popc(keep) < POST_NMS);
      #pragma unroll
      for (int j = 0; j < k; ++j)
        kb = kb && !(((keep >> j) & 1u) && ((sup[j] >> k) & 1u));
      keep |= (u32)(kb ? 1u : 0u) << k;
    }
    // (6) OR kept rows, record indices
    u64 orv = 0ull;
    #pragma unroll
    for (int s = 0; s < WIN; ++s)
      if ((keep >> s) & 1u) orv |= r[s];
    removed |= orv;
    if (lane == 0) {
      int c = nk;
      #pragma unroll
      for (int s = 0; s < WIN; ++s)
        if ((keep >> s) & 1u) s_kept[c++] = (u32)wi[s];
    }
    nk += (int)__popc(keep);
    // (7) rotate window
    bool allsent = true;
    #pragma unroll
    for (int s = 0; s < WIN; ++s) {
      wi[s] = ni[s];
      r[s]  = nr[s];
      allsent = allsent && (ni[s] >= PRE_NMS);
    }
    if (allsent) break;
  }

  __syncthreads();
  // emit first nk kept (ascending candidate rank = score order), zero-pad
  float4* outv = (float4*)out;
  for (int t = lane; t < POST_NMS; t += 64) {
    float4 v = make_float4(0.f, 0.f, 0.f, 0.f);
    if (t < nk) v = boxes_ws[b * PRE_NMS + s_kept[t]];
    outv[b * POST_NMS + t] = v;
  }
}

// ---------------------------------------------------------------------------
// Fallback: round-1 monolithic kernel (verified) if ws is too small.
// ---------------------------------------------------------------------------
__global__ void __launch_bounds__(NTH)
rpn_proposal_mono(const float* __restrict__ scores,
                  const float* __restrict__ deltas,
                  float* __restrict__ out)
{
  __shared__ __align__(16) char smem[16384 + 32768 + 4096];
  u32* s_hist = (u32*)smem;
  u64* s_cand = (u64*)(smem + 16384);
  u32* s_sfx  = (u32*)(smem + 16384 + 32768);
  float4* s_box = (float4*)smem;
  __shared__ u32 s_kept[POST_NMS];
  __shared__ u32 s_meta[4];

  const int tid = threadIdx.x;
  const int b   = blockIdx.x;
  const float* sc = scores + b * NBOX;

  for (int t = tid; t < NBUCKET; t += NTH) s_hist[t] = 0;
  if (tid < 4) s_meta[tid] = 0;
  __syncthreads();
  for (int m = 0; m < PER; ++m) {
    int i = tid + m * NTH;
    if (i < NBOX) {
      float s = sc[i];
      int bk = (int)(s * (float)NBUCKET);
      bk = bk < 0 ? 0 : (bk > NBUCKET - 1 ? NBUCKET - 1 : bk);
      atomicAdd(&s_hist[bk], 1u);
    }
  }
  __syncthreads();
  {
    u32 g = s_hist[4*tid] + s_hist[4*tid+1] + s_hist[4*tid+2] + s_hist[4*tid+3];
    s_sfx[tid] = g;
  }
  __syncthreads();
  for (int d = 1; d < NTH; d <<= 1) {
    u32 v = (tid + d < NTH) ? s_sfx[tid + d] : 0u;
    __syncthreads();
    s_sfx[tid] += v;
    __syncthreads();
  }
  {
    u32 sg  = s_sfx[tid];
    u32 sgn = (tid < NTH - 1) ? s_sfx[tid + 1] : 0u;
    if (sg >= PRE_NMS && sgn < PRE_NMS) {
      u32 c = sgn;
      for (int t = 4 * tid + 3; t >= 4 * tid; --t) {
        c += s_hist[t];
        if (c >= PRE_NMS) { s_meta[0] = (u32)t; s_meta[1] = c; break; }
      }
    }
  }
  __syncthreads();
  const u32 T = s_meta[0];
  for (int m = 0; m < PER; ++m) {
    int i = tid + m * NTH;
    if (i < NBOX) {
      float s = sc[i];
      int bk = (int)(s * (float)NBUCKET);
      bk = bk < 0 ? 0 : (bk > NBUCKET - 1 ? NBUCKET - 1 : bk);
      if ((u32)bk >= T) {
        u32 pos = atomicAdd(&s_meta[2], 1u);
        if (pos < SEGCAP) {
          u64 key = ((u64)__float_as_uint(s) << 32) | (u32)(~(u32)i);
          s_cand[pos] = key;
        }
      }
    }
  }
  __syncthreads();
  {
    u32 C = s_meta[2]; if (C > SEGCAP) C = SEGCAP;
    for (u32 p = C + tid; p < SEGCAP; p += NTH) s_cand[p] = 0ull;
  }
  for (int kk = 2; kk <= SEGCAP; kk <<= 1) {
    for (int j = kk >> 1; j > 0; j >>= 1) {
      __syncthreads();
      #pragma unroll
      for (int m = 0; m < 2; ++m) {
        int t = tid + m * NTH;
        int i = ((t & ~(j - 1)) << 1) | (t & (j - 1));
        int p = i | j;
        u64 a  = s_cand[i];
        u64 bb = s_cand[p];
        bool desc = (i & kk) == 0;
        bool sw = desc ? (a < bb) : (a > bb);
        if (sw) { s_cand[i] = bb; s_cand[p] = a; }
      }
    }
  }
  __syncthreads();
  const float* dl = deltas + b * (4 * NA * HW);
  float4 bx[3];
  #pragma unroll
  for (int m = 0; m < 3; ++m) {
    int k = tid + m * NTH;
    if (k < PRE_NMS) {
      u64 key = s_cand[k];
      bx[m] = decode_box(dl, (int)(~(u32)key));
    }
  }
  __syncthreads();
  #pragma unroll
  for (int m = 0; m < 3; ++m) {
    int k = tid + m * NTH;
    if (k < PRE_NMS) s_box[k] = bx[m];
  }
  __syncthreads();
  if (tid < 64) {
    const int lane = tid;
    float4 kb[5];
    float  ka[5];
    int nk = 0;
    for (int i = 0; i < PRE_NMS; ++i) {
      if (nk >= POST_NMS) break;
      float4 c = s_box[i];
      float carea = (c.z - c.x) * (c.w - c.y);
      bool over = false;
      #pragma unroll
      for (int s = 0; s < 5; ++s) {
        if (s * 64 < nk) {
          if (s * 64 + lane < nk) {
            float iw = fminf(kb[s].z, c.z) - fmaxf(kb[s].x, c.x);
            float ih = fminf(kb[s].w, c.w) - fmaxf(kb[s].y, c.y);
            iw = fmaxf(iw, 0.0f);
            ih = fmaxf(ih, 0.0f);
            float inter = iw * ih;
            float uni = ka[s] + carea - inter;
            over = over || (inter > 0.7f * fmaxf(uni, 1e-8f));
          }
        }
      }
      if (__ballot((int)over) == 0ull) {
        int s = nk >> 6, l = nk & 63;
        #pragma unroll
        for (int q = 0; q < 5; ++q)
          if (q == s && lane == l) { kb[q] = c; ka[q] = carea; }
        if (lane == 0) s_kept[nk] = (u32)i;
        ++nk;
      }
    }
    if (lane == 0) s_meta[3] = (u32)nk;
  }
  __syncthreads();
  if (tid < POST_NMS) {
    u32 nk = s_meta[3];
    float4 v = make_float4(0.0f, 0.0f, 0.0f, 0.0f);
    if ((u32)tid < nk) v = s_box[s_kept[tid]];
    ((float4*)out)[b * POST_NMS + tid] = v;
  }
}

extern "C" void kernel_launch(void* const* d_in, const int* in_sizes, int n_in,
                              void* d_out, int out_size, void* d_ws, size_t ws_size,
                              hipStream_t stream) {
  const float* scores = (const float*)d_in[0];
  const float* deltas = (const float*)d_in[1];
  (void)in_sizes; (void)n_in; (void)out_size;

  const size_t mask_off   = 196608;                                      // 192KB aligned
  const size_t mask_bytes = (size_t)NB * PRE_NMS * MWORDS * sizeof(u64); // 4.6MB
  const size_t need       = mask_off + mask_bytes;

  if (ws_size >= need) {
    float4* boxes_ws = (float4*)d_ws;
    u64*    masks    = (u64*)((char*)d_ws + mask_off);
    topk_rank_decode_kernel<<<dim3(NB), dim3(NTH), 0, stream>>>(scores, deltas, boxes_ws);
    mask_kernel<<<dim3(47, 12, NB), dim3(256), 0, stream>>>(boxes_ws, masks);
    nms_reduce_kernel<<<dim3(NB), dim3(64), 0, stream>>>(boxes_ws, masks, (float*)d_out);
  } else {
    rpn_proposal_mono<<<dim3(NB), dim3(NTH), 0, stream>>>(scores, deltas, (float*)d_out);
  }
}

// Round 5
// 190.987 us; speedup vs baseline: 1.8964x; 1.1362x over previous
//
#include <hip/hip_runtime.h>
#include <stdint.h>

typedef uint32_t u32;
typedef uint64_t u64;

#define NB 4
#define NA 9
#define NH 34
#define NW 60
#define HW (NH*NW)            // 2040
#define NBOX (NA*HW)          // 18360
#define PRE_NMS 3000
#define POST_NMS 300
#define NBUCKET 4096
#define SEGCAP 4096
#define NTH 1024
#define PER 18                // 18*1024 = 18432 >= 18360
#define MWORDS 48             // 48*64 = 3072 >= 3000 candidate bits per mask row
#define SUB 16                // candidates per serial sub-chunk in the reduce
#define NSUB 188              // ceil(3000/16)

// Anchor widths/heights (f64->f32 roundings, matching np.array(..., float32)).
__device__ __constant__ float c_aw[9] = {
  45.254833995939045f, 64.0f,  90.50966799187808f,
  90.50966799187808f,  128.0f, 181.01933598375617f,
  181.01933598375617f, 256.0f, 362.03867196751233f };
__device__ __constant__ float c_ah[9] = {
  90.50966799187808f,  64.0f,  45.254833995939045f,
  181.01933598375617f, 128.0f, 90.50966799187808f,
  362.03867196751233f, 256.0f, 181.01933598375617f };

__device__ __forceinline__ u64 readlane64(u64 v, int lane) {
  u32 lo = __builtin_amdgcn_readlane((u32)(v & 0xffffffffull), lane);
  u32 hi = __builtin_amdgcn_readlane((u32)(v >> 32), lane);
  return ((u64)hi << 32) | lo;
}

__device__ __forceinline__ float4 decode_box(const float* __restrict__ dl, int idx) {
  int a = idx / HW;
  int r = idx - a * HW;
  int h = r / NW;
  int w = r - h * NW;
  const float* dp = dl + (4 * a) * HW + r;
  float tx = dp[0];
  float ty = dp[HW];
  float tw = dp[2 * HW];
  float th = dp[3 * HW];
  float aw = c_aw[a], ah = c_ah[a];
  float ctr_x = ((float)w + 0.5f) * 16.0f + tx * aw;
  float ctr_y = ((float)h + 0.5f) * 16.0f + ty * ah;
  float w1 = expf(tw) * aw;
  float h1 = expf(th) * ah;
  float x1 = ctr_x - 0.5f * w1;
  float y1 = ctr_y - 0.5f * h1;
  float x2 = x1 + w1;
  float y2 = y1 + h1;
  x1 = fminf(fmaxf(x1, 0.0f), 959.0f);
  x2 = fminf(fmaxf(x2, 0.0f), 959.0f);
  y1 = fminf(fmaxf(y1, 0.0f), 543.0f);
  y2 = fminf(fmaxf(y2, 0.0f), 543.0f);
  return make_float4(x1, y1, x2, y2);
}

// ---------------------------------------------------------------------------
// K1 v2: sort-free exact ranking (unchanged from round 4 — verified).
// ---------------------------------------------------------------------------
__global__ void __launch_bounds__(NTH)
topk_rank_decode_kernel(const float* __restrict__ scores,
                        const float* __restrict__ deltas,
                        float4* __restrict__ boxes_ws)
{
  __shared__ u32 s_base[NBUCKET];
  __shared__ u32 s_cnt[NBUCKET];
  __shared__ u64 s_keys[SEGCAP];
  __shared__ u32 s_sfx[NTH];

  const int tid = threadIdx.x;
  const int b   = blockIdx.x;
  const float* sc = scores + b * NBOX;

  for (int t = tid; t < NBUCKET; t += NTH) s_cnt[t] = 0;
  __syncthreads();

  for (int m = 0; m < PER; ++m) {
    int i = tid + m * NTH;
    if (i < NBOX) {
      float s = sc[i];
      int bk = (int)(s * (float)NBUCKET);
      bk = bk < 0 ? 0 : (bk > NBUCKET - 1 ? NBUCKET - 1 : bk);
      atomicAdd(&s_cnt[bk], 1u);
    }
  }
  __syncthreads();

  u32 h0 = s_cnt[4*tid], h1 = s_cnt[4*tid+1], h2 = s_cnt[4*tid+2], h3 = s_cnt[4*tid+3];
  s_sfx[tid] = h0 + h1 + h2 + h3;
  __syncthreads();
  for (int d = 1; d < NTH; d <<= 1) {
    u32 v = (tid + d < NTH) ? s_sfx[tid + d] : 0u;
    __syncthreads();
    s_sfx[tid] += v;
    __syncthreads();
  }

  {
    u32 Gn = (tid < NTH - 1) ? s_sfx[tid + 1] : 0u;
    s_base[4*tid+3] = Gn;
    s_base[4*tid+2] = Gn + h3;
    s_base[4*tid+1] = Gn + h3 + h2;
    s_base[4*tid+0] = Gn + h3 + h2 + h1;
  }
  __syncthreads();

  for (int t = tid; t < NBUCKET; t += NTH) s_cnt[t] = 0;
  for (int t = tid; t < SEGCAP; t += NTH) s_keys[t] = 0ull;
  __syncthreads();

  for (int m = 0; m < PER; ++m) {
    int i = tid + m * NTH;
    if (i < NBOX) {
      float s = sc[i];
      int bk = (int)(s * (float)NBUCKET);
      bk = bk < 0 ? 0 : (bk > NBUCKET - 1 ? NBUCKET - 1 : bk);
      u32 base = s_base[bk];
      if (base < PRE_NMS) {
        u32 loc = atomicAdd(&s_cnt[bk], 1u);
        u32 pos = base + loc;
        if (pos < SEGCAP) {
          u64 key = ((u64)__float_as_uint(s) << 32) | (u32)(~(u32)i);
          s_keys[pos] = key;
        }
      }
    }
  }
  __syncthreads();

  const float* dl = deltas + b * (4 * NA * HW);
  for (int m = 0; m < SEGCAP / NTH; ++m) {
    int p = tid + m * NTH;
    u64 key = s_keys[p];
    float s = __uint_as_float((u32)(key >> 32));
    int bk = (int)(s * (float)NBUCKET);
    bk = bk < 0 ? 0 : (bk > NBUCKET - 1 ? NBUCKET - 1 : bk);
    u32 base = s_base[bk];
    u32 cnt  = s_cnt[bk];
    u32 local = 0;
    for (u32 q = base; q < base + cnt; ++q)
      local += (s_keys[q] > key) ? 1u : 0u;
    u32 R = base + local;
    if (key != 0ull && R < PRE_NMS) {
      int idx = (int)(~(u32)key);
      boxes_ws[b * PRE_NMS + R] = decode_box(dl, idx);
    }
  }
}

// ---------------------------------------------------------------------------
// K2: suppression bit-matrix (unchanged). mask[b][i][c] bit k = IoU>0.7.
// ---------------------------------------------------------------------------
__global__ void __launch_bounds__(256)
mask_kernel(const float4* __restrict__ boxes_ws, u64* __restrict__ masks)
{
  const int b = blockIdx.z, c = blockIdx.x;
  const int tid = threadIdx.x;
  __shared__ float4 s_cb[64];
  __shared__ float  s_ca[64];
  if (tid < 64) {
    int j = c * 64 + tid;
    float4 v = (j < PRE_NMS) ? boxes_ws[b * PRE_NMS + j]
                             : make_float4(0.f, 0.f, 0.f, 0.f);
    s_cb[tid] = v;
    s_ca[tid] = (v.z - v.x) * (v.w - v.y);
  }
  __syncthreads();
  int row = blockIdx.y * 250 + tid;
  if (tid < 250 && row < PRE_NMS) {
    float4 r = boxes_ws[b * PRE_NMS + row];
    float ra = (r.z - r.x) * (r.w - r.y);
    u64 word = 0;
    #pragma unroll
    for (int k = 0; k < 64; ++k) {
      float4 cb = s_cb[k];
      float iw = fminf(r.z, cb.z) - fmaxf(r.x, cb.x);
      float ih = fminf(r.w, cb.w) - fmaxf(r.y, cb.y);
      iw = fmaxf(iw, 0.0f);
      ih = fmaxf(ih, 0.0f);
      float inter = iw * ih;
      float uni = ra + s_ca[k] - inter;
      word |= ((u64)(inter > 0.7f * fmaxf(uni, 1e-8f))) << k;
    }
    masks[((size_t)b * PRE_NMS + row) * MWORDS + c] = word;
  }
}

// ---------------------------------------------------------------------------
// K3 v4: contiguous sub-chunk greedy reduce (16 candidates / serial step).
// Lane w owns removed word w. Ring of 3 statically-indexed row buffers
// R0/R1/R2, each = 16 rows x (word `lane`), loaded COALESCED (lane l <->
// word l of the row-major mask matrix), prefetched 3 sub-chunks ahead.
// Per sub-chunk: 1 readlane (avail16), uniform keep chain over set bits
// (1 readlane64 per KEPT row only — its word base>>6 carries all intra-chunk
// suppression bits), <=16 v_or_b64 merge, 16 coalesced refill loads.
// One vmcnt wait per 16 candidates instead of per pop.
// Exact greedy NMS: only kept rows OR'd, ascending rank order, gate at 300.
// ---------------------------------------------------------------------------
__global__ void __launch_bounds__(64)
nms_reduce_kernel(const float4* __restrict__ boxes_ws,
                  const u64* __restrict__ masks,
                  float* __restrict__ out)
{
  const int b = blockIdx.x;
  const int lane = threadIdx.x;
  __shared__ u32 s_kept[POST_NMS];

  // removed bitmap: lane w owns bits [64w, 64w+64). Bits >= 3000 pre-set.
  u64 removed;
  if (lane < 46)       removed = 0ull;
  else if (lane == 46) removed = ~((1ull << 56) - 1);   // bits 3000..3007
  else                 removed = ~0ull;

  const u64* mrow = masks + (size_t)b * PRE_NMS * MWORDS;
  const bool ld = (lane < 47);

  u64 R0[SUB], R1[SUB], R2[SUB];
  #pragma unroll
  for (int r = 0; r < SUB; ++r)
    R0[r] = ld ? mrow[(size_t)(0 * SUB + r) * MWORDS + lane] : 0ull;
  #pragma unroll
  for (int r = 0; r < SUB; ++r)
    R1[r] = ld ? mrow[(size_t)(1 * SUB + r) * MWORDS + lane] : 0ull;
  #pragma unroll
  for (int r = 0; r < SUB; ++r)
    R2[r] = ld ? mrow[(size_t)(2 * SUB + r) * MWORDS + lane] : 0ull;

  int nk = 0;

  auto step = [&](u64 (&R)[SUB], int j) -> bool {
    const int base = j * SUB;
    const int w0 = base >> 6;
    const int sh = base & 63;
    // validate all 16 candidates vs accumulated removed bitmap
    u64 remw = readlane64(removed, w0);
    u32 a = (u32)((~remw >> sh) & 0xFFFFull);
    // uniform keep chain; supw carries intra-chunk suppression bits
    u64 supw = 0ull;
    u32 keepm = 0;
    while (a) {
      int k = __ffs(a) - 1;
      a &= a - 1u;
      if (!((supw >> (sh + k)) & 1ull)) {
        keepm |= 1u << k;
        if (lane == 0) s_kept[nk] = (u32)(base + k);
        ++nk;
        if (nk >= POST_NMS) break;
        supw |= readlane64(R[k], w0);
      }
    }
    // merge kept rows into removed (per-lane VALU)
    u64 orv = 0ull;
    #pragma unroll
    for (int r = 0; r < SUB; ++r)
      if ((keepm >> r) & 1u) orv |= R[r];
    removed |= orv;
    if (nk >= POST_NMS) return true;
    // refill this slot with sub-chunk j+3 (consumed 3 steps later)
    const int nbase = (j + 3) * SUB;
    #pragma unroll
    for (int r = 0; r < SUB; ++r) {
      int row = nbase + r;
      R[r] = (ld && row < PRE_NMS) ? mrow[(size_t)row * MWORDS + lane] : 0ull;
    }
    return false;
  };

  bool done = false;
  for (int j = 0; j < NSUB && !done; j += 3) {
    done = step(R0, j);
    if (!done && j + 1 < NSUB) done = step(R1, j + 1);
    if (!done && j + 2 < NSUB) done = step(R2, j + 2);
  }

  __syncthreads();
  // emit first nk kept (ascending rank = score desc), zero-pad to 300
  float4* outv = (float4*)out;
  for (int t = lane; t < POST_NMS; t += 64) {
    float4 v = make_float4(0.f, 0.f, 0.f, 0.f);
    if (t < nk) v = boxes_ws[b * PRE_NMS + s_kept[t]];
    outv[b * POST_NMS + t] = v;
  }
}

// ---------------------------------------------------------------------------
// Fallback: round-1 monolithic kernel (verified) if ws is too small.
// ---------------------------------------------------------------------------
__global__ void __launch_bounds__(NTH)
rpn_proposal_mono(const float* __restrict__ scores,
                  const float* __restrict__ deltas,
                  float* __restrict__ out)
{
  __shared__ __align__(16) char smem[16384 + 32768 + 4096];
  u32* s_hist = (u32*)smem;
  u64* s_cand = (u64*)(smem + 16384);
  u32* s_sfx  = (u32*)(smem + 16384 + 32768);
  float4* s_box = (float4*)smem;
  __shared__ u32 s_kept[POST_NMS];
  __shared__ u32 s_meta[4];

  const int tid = threadIdx.x;
  const int b   = blockIdx.x;
  const float* sc = scores + b * NBOX;

  for (int t = tid; t < NBUCKET; t += NTH) s_hist[t] = 0;
  if (tid < 4) s_meta[tid] = 0;
  __syncthreads();
  for (int m = 0; m < PER; ++m) {
    int i = tid + m * NTH;
    if (i < NBOX) {
      float s = sc[i];
      int bk = (int)(s * (float)NBUCKET);
      bk = bk < 0 ? 0 : (bk > NBUCKET - 1 ? NBUCKET - 1 : bk);
      atomicAdd(&s_hist[bk], 1u);
    }
  }
  __syncthreads();
  {
    u32 g = s_hist[4*tid] + s_hist[4*tid+1] + s_hist[4*tid+2] + s_hist[4*tid+3];
    s_sfx[tid] = g;
  }
  __syncthreads();
  for (int d = 1; d < NTH; d <<= 1) {
    u32 v = (tid + d < NTH) ? s_sfx[tid + d] : 0u;
    __syncthreads();
    s_sfx[tid] += v;
    __syncthreads();
  }
  {
    u32 sg  = s_sfx[tid];
    u32 sgn = (tid < NTH - 1) ? s_sfx[tid + 1] : 0u;
    if (sg >= PRE_NMS && sgn < PRE_NMS) {
      u32 c = sgn;
      for (int t = 4 * tid + 3; t >= 4 * tid; --t) {
        c += s_hist[t];
        if (c >= PRE_NMS) { s_meta[0] = (u32)t; s_meta[1] = c; break; }
      }
    }
  }
  __syncthreads();
  const u32 T = s_meta[0];
  for (int m = 0; m < PER; ++m) {
    int i = tid + m * NTH;
    if (i < NBOX) {
      float s = sc[i];
      int bk = (int)(s * (float)NBUCKET);
      bk = bk < 0 ? 0 : (bk > NBUCKET - 1 ? NBUCKET - 1 : bk);
      if ((u32)bk >= T) {
        u32 pos = atomicAdd(&s_meta[2], 1u);
        if (pos < SEGCAP) {
          u64 key = ((u64)__float_as_uint(s) << 32) | (u32)(~(u32)i);
          s_cand[pos] = key;
        }
      }
    }
  }
  __syncthreads();
  {
    u32 C = s_meta[2]; if (C > SEGCAP) C = SEGCAP;
    for (u32 p = C + tid; p < SEGCAP; p += NTH) s_cand[p] = 0ull;
  }
  for (int kk = 2; kk <= SEGCAP; kk <<= 1) {
    for (int j = kk >> 1; j > 0; j >>= 1) {
      __syncthreads();
      #pragma unroll
      for (int m = 0; m < 2; ++m) {
        int t = tid + m * NTH;
        int i = ((t & ~(j - 1)) << 1) | (t & (j - 1));
        int p = i | j;
        u64 a  = s_cand[i];
        u64 bb = s_cand[p];
        bool desc = (i & kk) == 0;
        bool sw = desc ? (a < bb) : (a > bb);
        if (sw) { s_cand[i] = bb; s_cand[p] = a; }
      }
    }
  }
  __syncthreads();
  const float* dl = deltas + b * (4 * NA * HW);
  float4 bx[3];
  #pragma unroll
  for (int m = 0; m < 3; ++m) {
    int k = tid + m * NTH;
    if (k < PRE_NMS) {
      u64 key = s_cand[k];
      bx[m] = decode_box(dl, (int)(~(u32)key));
    }
  }
  __syncthreads();
  #pragma unroll
  for (int m = 0; m < 3; ++m) {
    int k = tid + m * NTH;
    if (k < PRE_NMS) s_box[k] = bx[m];
  }
  __syncthreads();
  if (tid < 64) {
    const int lane = tid;
    float4 kb[5];
    float  ka[5];
    int nk = 0;
    for (int i = 0; i < PRE_NMS; ++i) {
      if (nk >= POST_NMS) break;
      float4 c = s_box[i];
      float carea = (c.z - c.x) * (c.w - c.y);
      bool over = false;
      #pragma unroll
      for (int s = 0; s < 5; ++s) {
        if (s * 64 < nk) {
          if (s * 64 + lane < nk) {
            float iw = fminf(kb[s].z, c.z) - fmaxf(kb[s].x, c.x);
            float ih = fminf(kb[s].w, c.w) - fmaxf(kb[s].y, c.y);
            iw = fmaxf(iw, 0.0f);
            ih = fmaxf(ih, 0.0f);
            float inter = iw * ih;
            float uni = ka[s] + carea - inter;
            over = over || (inter > 0.7f * fmaxf(uni, 1e-8f));
          }
        }
      }
      if (__ballot((int)over) == 0ull) {
        int s = nk >> 6, l = nk & 63;
        #pragma unroll
        for (int q = 0; q < 5; ++q)
          if (q == s && lane == l) { kb[q] = c; ka[q] = carea; }
        if (lane == 0) s_kept[nk] = (u32)i;
        ++nk;
      }
    }
    if (lane == 0) s_meta[3] = (u32)nk;
  }
  __syncthreads();
  if (tid < POST_NMS) {
    u32 nk = s_meta[3];
    float4 v = make_float4(0.0f, 0.0f, 0.0f, 0.0f);
    if ((u32)tid < nk) v = s_box[s_kept[tid]];
    ((float4*)out)[b * POST_NMS + tid] = v;
  }
}

extern "C" void kernel_launch(void* const* d_in, const int* in_sizes, int n_in,
                              void* d_out, int out_size, void* d_ws, size_t ws_size,
                              hipStream_t stream) {
  const float* scores = (const float*)d_in[0];
  const float* deltas = (const float*)d_in[1];
  (void)in_sizes; (void)n_in; (void)out_size;

  const size_t mask_off   = 196608;                                      // 192KB aligned
  const size_t mask_bytes = (size_t)NB * PRE_NMS * MWORDS * sizeof(u64); // 4.6MB
  const size_t need       = mask_off + mask_bytes;

  if (ws_size >= need) {
    float4* boxes_ws = (float4*)d_ws;
    u64*    masks    = (u64*)((char*)d_ws + mask_off);
    topk_rank_decode_kernel<<<dim3(NB), dim3(NTH), 0, stream>>>(scores, deltas, boxes_ws);
    mask_kernel<<<dim3(47, 12, NB), dim3(256), 0, stream>>>(boxes_ws, masks);
    nms_reduce_kernel<<<dim3(NB), dim3(64), 0, stream>>>(boxes_ws, masks, (float*)d_out);
  } else {
    rpn_proposal_mono<<<dim3(NB), dim3(NTH), 0, stream>>>(scores, deltas, (float*)d_out);
  }
}

// Round 6
// 146.283 us; speedup vs baseline: 2.4759x; 1.3056x over previous
//
#include <hip/hip_runtime.h>
#include <stdint.h>

typedef uint32_t u32;
typedef uint64_t u64;

#define NB 4
#define NA 9
#define NH 34
#define NW 60
#define HW (NH*NW)            // 2040
#define NBOX (NA*HW)          // 18360
#define PRE_NMS 3000
#define POST_NMS 300
#define NBUCKET 4096
#define SEGCAP 4096
#define NTH 1024
#define PER 18                // 18*1024 = 18432 >= 18360
#define CORNER 512            // examined-candidate corner (fallback covers rest)
#define CW 8                  // words per corner row (512/64)
#define SUB 16                // candidates per serial sub-chunk
#define NCH (CORNER/SUB)      // 32 sub-chunks

// Anchor widths/heights (f64->f32 roundings, matching np.array(..., float32)).
__device__ __constant__ float c_aw[9] = {
  45.254833995939045f, 64.0f,  90.50966799187808f,
  90.50966799187808f,  128.0f, 181.01933598375617f,
  181.01933598375617f, 256.0f, 362.03867196751233f };
__device__ __constant__ float c_ah[9] = {
  90.50966799187808f,  64.0f,  45.254833995939045f,
  181.01933598375617f, 128.0f, 90.50966799187808f,
  362.03867196751233f, 256.0f, 181.01933598375617f };

__device__ __forceinline__ u64 readlane64(u64 v, int lane) {
  u32 lo = __builtin_amdgcn_readlane((u32)(v & 0xffffffffull), lane);
  u32 hi = __builtin_amdgcn_readlane((u32)(v >> 32), lane);
  return ((u64)hi << 32) | lo;
}

__device__ __forceinline__ float4 decode_box(const float* __restrict__ dl, int idx) {
  int a = idx / HW;
  int r = idx - a * HW;
  int h = r / NW;
  int w = r - h * NW;
  const float* dp = dl + (4 * a) * HW + r;
  float tx = dp[0];
  float ty = dp[HW];
  float tw = dp[2 * HW];
  float th = dp[3 * HW];
  float aw = c_aw[a], ah = c_ah[a];
  float ctr_x = ((float)w + 0.5f) * 16.0f + tx * aw;
  float ctr_y = ((float)h + 0.5f) * 16.0f + ty * ah;
  float w1 = expf(tw) * aw;
  float h1 = expf(th) * ah;
  float x1 = ctr_x - 0.5f * w1;
  float y1 = ctr_y - 0.5f * h1;
  float x2 = x1 + w1;
  float y2 = y1 + h1;
  x1 = fminf(fmaxf(x1, 0.0f), 959.0f);
  x2 = fminf(fmaxf(x2, 0.0f), 959.0f);
  y1 = fminf(fmaxf(y1, 0.0f), 543.0f);
  y2 = fminf(fmaxf(y2, 0.0f), 543.0f);
  return make_float4(x1, y1, x2, y2);
}

// ---------------------------------------------------------------------------
// K1: sort-free exact ranking (verified rounds 4-5, unchanged).
// ---------------------------------------------------------------------------
__global__ void __launch_bounds__(NTH)
topk_rank_decode_kernel(const float* __restrict__ scores,
                        const float* __restrict__ deltas,
                        float4* __restrict__ boxes_ws)
{
  __shared__ u32 s_base[NBUCKET];
  __shared__ u32 s_cnt[NBUCKET];
  __shared__ u64 s_keys[SEGCAP];
  __shared__ u32 s_sfx[NTH];

  const int tid = threadIdx.x;
  const int b   = blockIdx.x;
  const float* sc = scores + b * NBOX;

  for (int t = tid; t < NBUCKET; t += NTH) s_cnt[t] = 0;
  __syncthreads();

  for (int m = 0; m < PER; ++m) {
    int i = tid + m * NTH;
    if (i < NBOX) {
      float s = sc[i];
      int bk = (int)(s * (float)NBUCKET);
      bk = bk < 0 ? 0 : (bk > NBUCKET - 1 ? NBUCKET - 1 : bk);
      atomicAdd(&s_cnt[bk], 1u);
    }
  }
  __syncthreads();

  u32 h0 = s_cnt[4*tid], h1 = s_cnt[4*tid+1], h2 = s_cnt[4*tid+2], h3 = s_cnt[4*tid+3];
  s_sfx[tid] = h0 + h1 + h2 + h3;
  __syncthreads();
  for (int d = 1; d < NTH; d <<= 1) {
    u32 v = (tid + d < NTH) ? s_sfx[tid + d] : 0u;
    __syncthreads();
    s_sfx[tid] += v;
    __syncthreads();
  }

  {
    u32 Gn = (tid < NTH - 1) ? s_sfx[tid + 1] : 0u;
    s_base[4*tid+3] = Gn;
    s_base[4*tid+2] = Gn + h3;
    s_base[4*tid+1] = Gn + h3 + h2;
    s_base[4*tid+0] = Gn + h3 + h2 + h1;
  }
  __syncthreads();

  for (int t = tid; t < NBUCKET; t += NTH) s_cnt[t] = 0;
  for (int t = tid; t < SEGCAP; t += NTH) s_keys[t] = 0ull;
  __syncthreads();

  for (int m = 0; m < PER; ++m) {
    int i = tid + m * NTH;
    if (i < NBOX) {
      float s = sc[i];
      int bk = (int)(s * (float)NBUCKET);
      bk = bk < 0 ? 0 : (bk > NBUCKET - 1 ? NBUCKET - 1 : bk);
      u32 base = s_base[bk];
      if (base < PRE_NMS) {
        u32 loc = atomicAdd(&s_cnt[bk], 1u);
        u32 pos = base + loc;
        if (pos < SEGCAP) {
          u64 key = ((u64)__float_as_uint(s) << 32) | (u32)(~(u32)i);
          s_keys[pos] = key;
        }
      }
    }
  }
  __syncthreads();

  const float* dl = deltas + b * (4 * NA * HW);
  for (int m = 0; m < SEGCAP / NTH; ++m) {
    int p = tid + m * NTH;
    u64 key = s_keys[p];
    float s = __uint_as_float((u32)(key >> 32));
    int bk = (int)(s * (float)NBUCKET);
    bk = bk < 0 ? 0 : (bk > NBUCKET - 1 ? NBUCKET - 1 : bk);
    u32 base = s_base[bk];
    u32 cnt  = s_cnt[bk];
    u32 local = 0;
    for (u32 q = base; q < base + cnt; ++q)
      local += (s_keys[q] > key) ? 1u : 0u;
    u32 R = base + local;
    if (key != 0ull && R < PRE_NMS) {
      int idx = (int)(~(u32)key);
      boxes_ws[b * PRE_NMS + R] = decode_box(dl, idx);
    }
  }
}

// ---------------------------------------------------------------------------
// K2 v2: 512x512 suppression corner only. masks2[b][row][w], w<8.
// grid (4 word-pairs, 2 row-halves, NB) x 256 threads; ~128 IoU/thread.
// ---------------------------------------------------------------------------
__global__ void __launch_bounds__(256)
mask_corner_kernel(const float4* __restrict__ boxes_ws, u64* __restrict__ masks2)
{
  const int wq = blockIdx.x;          // word pair: words 2wq, 2wq+1
  const int rh = blockIdx.y;          // row half
  const int b  = blockIdx.z;
  const int tid = threadIdx.x;
  __shared__ float4 s_cb[128];
  __shared__ float  s_ca[128];
  if (tid < 128) {
    int j = 128 * wq + tid;           // col < 512 < PRE_NMS
    float4 v = boxes_ws[b * PRE_NMS + j];
    s_cb[tid] = v;
    s_ca[tid] = (v.z - v.x) * (v.w - v.y);
  }
  __syncthreads();
  int row = rh * 256 + tid;           // 0..511
  float4 r = boxes_ws[b * PRE_NMS + row];
  float ra = (r.z - r.x) * (r.w - r.y);
  #pragma unroll
  for (int wl = 0; wl < 2; ++wl) {
    u64 word = 0;
    #pragma unroll
    for (int k = 0; k < 64; ++k) {
      float4 cb = s_cb[wl * 64 + k];
      float iw = fminf(r.z, cb.z) - fmaxf(r.x, cb.x);
      float ih = fminf(r.w, cb.w) - fmaxf(r.y, cb.y);
      iw = fmaxf(iw, 0.0f);
      ih = fmaxf(ih, 0.0f);
      float inter = iw * ih;
      float uni = ra + s_ca[wl * 64 + k] - inter;
      word |= ((u64)(inter > 0.7f * fmaxf(uni, 1e-8f))) << k;
    }
    masks2[((size_t)b * CORNER + row) * CW + (2 * wq + wl)] = word;
  }
}

// ---------------------------------------------------------------------------
// K3 v5: LDS-corner greedy reduce. 256 threads: all fill the 32KB corner
// into LDS; wave 0 runs the serial chain on 16-candidate sub-chunks with a
// depth-2 ds_read ring. NO dynamic register-array indexing: the intra-chunk
// suppression word lives in one register D (lane k = word w0 of row base+k),
// accessed via readlane64(D,k) (runtime LANE index is legal in HW).
// Exact greedy; in-kernel fallback continues past candidate 512 if needed.
// ---------------------------------------------------------------------------
__global__ void __launch_bounds__(256)
nms_reduce_kernel(const float4* __restrict__ boxes_ws,
                  const u64* __restrict__ masks2,
                  float* __restrict__ out)
{
  const int b = blockIdx.x;
  const int tid = threadIdx.x;
  __shared__ __align__(16) u64 s_corner[CORNER * CW];   // 32 KB
  __shared__ u32 s_kept[POST_NMS];
  __shared__ u32 s_nk;

  // ---- phase A: corner -> LDS (coalesced, 256 threads) ----
  {
    const ulonglong2* src = (const ulonglong2*)(masks2 + (size_t)b * CORNER * CW);
    ulonglong2* dst = (ulonglong2*)s_corner;
    #pragma unroll
    for (int k = 0; k < (CORNER * CW / 2) / 256; ++k)
      dst[tid + k * 256] = src[tid + k * 256];
  }
  __syncthreads();

  // ---- phase B: wave-0 serial greedy over corner ----
  if (tid < 64) {
    const int lane = tid;
    const int wl8  = lane & 7;    // row-word each lane tracks
    const int wl16 = lane & 15;   // diag position each lane tracks
    u64 removed = 0ull;           // lanes 0-7 meaningful (512 bits)
    int nk = 0;

    u64 Ra[SUB], Rb[SUB], Da, Db;
    #pragma unroll
    for (int r = 0; r < SUB; ++r) Ra[r] = s_corner[(0 * SUB + r) * CW + wl8];
    Da = s_corner[(0 * SUB + wl16) * CW + 0];
    #pragma unroll
    for (int r = 0; r < SUB; ++r) Rb[r] = s_corner[(1 * SUB + r) * CW + wl8];
    Db = s_corner[(1 * SUB + wl16) * CW + 0];

#define NMS_STEP(Rr, Dd, J)                                                   \
    {                                                                         \
      const int base = (J) * SUB;                                             \
      const int w0 = (J) >> 2;                                                \
      const int sh = ((J) & 3) * 16;                                          \
      u64 remw = readlane64(removed, w0);                                     \
      u32 a = (u32)((~remw >> sh) & 0xFFFFull);                               \
      u64 supw = 0ull;                                                        \
      u32 keepm = 0;                                                          \
      while (a) {                                                             \
        int k = __ffs(a) - 1;                                                 \
        a &= a - 1u;                                                          \
        if (!((supw >> (sh + k)) & 1ull)) {                                   \
          keepm |= 1u << k;                                                   \
          if (lane == 0) s_kept[nk] = (u32)(base + k);                        \
          ++nk;                                                               \
          if (nk >= POST_NMS) break;                                          \
          supw |= readlane64(Dd, k);                                          \
        }                                                                     \
      }                                                                       \
      u64 orv = 0ull;                                                         \
      _Pragma("unroll")                                                       \
      for (int r = 0; r < SUB; ++r)                                           \
        if ((keepm >> r) & 1u) orv |= Rr[r];                                  \
      removed |= orv;                                                         \
      done = (nk >= POST_NMS);                                                \
      if (!done) {                                                            \
        const int nj = (J) + 2;                                               \
        if (nj < NCH) {                                                       \
          const int nb = nj * SUB;                                            \
          _Pragma("unroll")                                                   \
          for (int r = 0; r < SUB; ++r)                                       \
            Rr[r] = s_corner[(nb + r) * CW + wl8];                            \
          Dd = s_corner[(nb + wl16) * CW + (nj >> 2)];                        \
        }                                                                     \
      }                                                                       \
    }

    bool done = false;
    for (int j = 0; j < NCH && !done; j += 2) {
      NMS_STEP(Ra, Da, j)
      if (!done) { NMS_STEP(Rb, Db, j + 1) }
    }
#undef NMS_STEP

    // ---- phase C: exact fallback past candidate 512 (not taken on this
    // data; correctness net). Round-1-verified register-NMS logic. ----
    if (nk < POST_NMS) {
      float4 kb[5];
      float  ka[5];
      #pragma unroll
      for (int s = 0; s < 5; ++s) {
        int t = s * 64 + lane;
        float4 v = make_float4(0.f, 0.f, 0.f, 0.f);
        if (t < nk) v = boxes_ws[b * PRE_NMS + s_kept[t]];
        kb[s] = v;
        ka[s] = (v.z - v.x) * (v.w - v.y);
      }
      for (int i = CORNER; i < PRE_NMS; ++i) {
        if (nk >= POST_NMS) break;
        float4 c = boxes_ws[b * PRE_NMS + i];   // uniform address
        float carea = (c.z - c.x) * (c.w - c.y);
        bool over = false;
        #pragma unroll
        for (int s = 0; s < 5; ++s) {
          if (s * 64 < nk) {
            if (s * 64 + lane < nk) {
              float iw = fminf(kb[s].z, c.z) - fmaxf(kb[s].x, c.x);
              float ih = fminf(kb[s].w, c.w) - fmaxf(kb[s].y, c.y);
              iw = fmaxf(iw, 0.0f);
              ih = fmaxf(ih, 0.0f);
              float inter = iw * ih;
              float uni = ka[s] + carea - inter;
              over = over || (inter > 0.7f * fmaxf(uni, 1e-8f));
            }
          }
        }
        if (__ballot((int)over) == 0ull) {
          int s = nk >> 6, l = nk & 63;
          #pragma unroll
          for (int q = 0; q < 5; ++q)
            if (q == s && lane == l) { kb[q] = c; ka[q] = carea; }
          if (lane == 0) s_kept[nk] = (u32)i;
          ++nk;
        }
      }
    }
    if (lane == 0) s_nk = (u32)nk;
  }
  __syncthreads();

  // ---- emit: first nk kept (score order), zero-pad to 300 ----
  u32 fnk = s_nk;
  float4* outv = (float4*)out;
  for (int t = tid; t < POST_NMS; t += 256) {
    float4 v = make_float4(0.f, 0.f, 0.f, 0.f);
    if ((u32)t < fnk) v = boxes_ws[b * PRE_NMS + s_kept[t]];
    outv[b * POST_NMS + t] = v;
  }
}

// ---------------------------------------------------------------------------
// Fallback: round-1 monolithic kernel (verified) if ws is too small.
// ---------------------------------------------------------------------------
__global__ void __launch_bounds__(NTH)
rpn_proposal_mono(const float* __restrict__ scores,
                  const float* __restrict__ deltas,
                  float* __restrict__ out)
{
  __shared__ __align__(16) char smem[16384 + 32768 + 4096];
  u32* s_hist = (u32*)smem;
  u64* s_cand = (u64*)(smem + 16384);
  u32* s_sfx  = (u32*)(smem + 16384 + 32768);
  float4* s_box = (float4*)smem;
  __shared__ u32 s_kept[POST_NMS];
  __shared__ u32 s_meta[4];

  const int tid = threadIdx.x;
  const int b   = blockIdx.x;
  const float* sc = scores + b * NBOX;

  for (int t = tid; t < NBUCKET; t += NTH) s_hist[t] = 0;
  if (tid < 4) s_meta[tid] = 0;
  __syncthreads();
  for (int m = 0; m < PER; ++m) {
    int i = tid + m * NTH;
    if (i < NBOX) {
      float s = sc[i];
      int bk = (int)(s * (float)NBUCKET);
      bk = bk < 0 ? 0 : (bk > NBUCKET - 1 ? NBUCKET - 1 : bk);
      atomicAdd(&s_hist[bk], 1u);
    }
  }
  __syncthreads();
  {
    u32 g = s_hist[4*tid] + s_hist[4*tid+1] + s_hist[4*tid+2] + s_hist[4*tid+3];
    s_sfx[tid] = g;
  }
  __syncthreads();
  for (int d = 1; d < NTH; d <<= 1) {
    u32 v = (tid + d < NTH) ? s_sfx[tid + d] : 0u;
    __syncthreads();
    s_sfx[tid] += v;
    __syncthreads();
  }
  {
    u32 sg  = s_sfx[tid];
    u32 sgn = (tid < NTH - 1) ? s_sfx[tid + 1] : 0u;
    if (sg >= PRE_NMS && sgn < PRE_NMS) {
      u32 c = sgn;
      for (int t = 4 * tid + 3; t >= 4 * tid; --t) {
        c += s_hist[t];
        if (c >= PRE_NMS) { s_meta[0] = (u32)t; s_meta[1] = c; break; }
      }
    }
  }
  __syncthreads();
  const u32 T = s_meta[0];
  for (int m = 0; m < PER; ++m) {
    int i = tid + m * NTH;
    if (i < NBOX) {
      float s = sc[i];
      int bk = (int)(s * (float)NBUCKET);
      bk = bk < 0 ? 0 : (bk > NBUCKET - 1 ? NBUCKET - 1 : bk);
      if ((u32)bk >= T) {
        u32 pos = atomicAdd(&s_meta[2], 1u);
        if (pos < SEGCAP) {
          u64 key = ((u64)__float_as_uint(s) << 32) | (u32)(~(u32)i);
          s_cand[pos] = key;
        }
      }
    }
  }
  __syncthreads();
  {
    u32 C = s_meta[2]; if (C > SEGCAP) C = SEGCAP;
    for (u32 p = C + tid; p < SEGCAP; p += NTH) s_cand[p] = 0ull;
  }
  for (int kk = 2; kk <= SEGCAP; kk <<= 1) {
    for (int j = kk >> 1; j > 0; j >>= 1) {
      __syncthreads();
      #pragma unroll
      for (int m = 0; m < 2; ++m) {
        int t = tid + m * NTH;
        int i = ((t & ~(j - 1)) << 1) | (t & (j - 1));
        int p = i | j;
        u64 a  = s_cand[i];
        u64 bb = s_cand[p];
        bool desc = (i & kk) == 0;
        bool sw = desc ? (a < bb) : (a > bb);
        if (sw) { s_cand[i] = bb; s_cand[p] = a; }
      }
    }
  }
  __syncthreads();
  const float* dl = deltas + b * (4 * NA * HW);
  float4 bx[3];
  #pragma unroll
  for (int m = 0; m < 3; ++m) {
    int k = tid + m * NTH;
    if (k < PRE_NMS) {
      u64 key = s_cand[k];
      bx[m] = decode_box(dl, (int)(~(u32)key));
    }
  }
  __syncthreads();
  #pragma unroll
  for (int m = 0; m < 3; ++m) {
    int k = tid + m * NTH;
    if (k < PRE_NMS) s_box[k] = bx[m];
  }
  __syncthreads();
  if (tid < 64) {
    const int lane = tid;
    float4 kb[5];
    float  ka[5];
    int nk = 0;
    for (int i = 0; i < PRE_NMS; ++i) {
      if (nk >= POST_NMS) break;
      float4 c = s_box[i];
      float carea = (c.z - c.x) * (c.w - c.y);
      bool over = false;
      #pragma unroll
      for (int s = 0; s < 5; ++s) {
        if (s * 64 < nk) {
          if (s * 64 + lane < nk) {
            float iw = fminf(kb[s].z, c.z) - fmaxf(kb[s].x, c.x);
            float ih = fminf(kb[s].w, c.w) - fmaxf(kb[s].y, c.y);
            iw = fmaxf(iw, 0.0f);
            ih = fmaxf(ih, 0.0f);
            float inter = iw * ih;
            float uni = ka[s] + carea - inter;
            over = over || (inter > 0.7f * fmaxf(uni, 1e-8f));
          }
        }
      }
      if (__ballot((int)over) == 0ull) {
        int s = nk >> 6, l = nk & 63;
        #pragma unroll
        for (int q = 0; q < 5; ++q)
          if (q == s && lane == l) { kb[q] = c; ka[q] = carea; }
        if (lane == 0) s_kept[nk] = (u32)i;
        ++nk;
      }
    }
    if (lane == 0) s_meta[3] = (u32)nk;
  }
  __syncthreads();
  if (tid < POST_NMS) {
    u32 nk = s_meta[3];
    float4 v = make_float4(0.0f, 0.0f, 0.0f, 0.0f);
    if ((u32)tid < nk) v = s_box[s_kept[tid]];
    ((float4*)out)[b * POST_NMS + tid] = v;
  }
}

extern "C" void kernel_launch(void* const* d_in, const int* in_sizes, int n_in,
                              void* d_out, int out_size, void* d_ws, size_t ws_size,
                              hipStream_t stream) {
  const float* scores = (const float*)d_in[0];
  const float* deltas = (const float*)d_in[1];
  (void)in_sizes; (void)n_in; (void)out_size;

  const size_t mask_off   = 196608;                                   // 192KB aligned
  const size_t mask_bytes = (size_t)NB * CORNER * CW * sizeof(u64);   // 128 KB
  const size_t need       = mask_off + mask_bytes;

  if (ws_size >= need) {
    float4* boxes_ws = (float4*)d_ws;
    u64*    masks2   = (u64*)((char*)d_ws + mask_off);
    topk_rank_decode_kernel<<<dim3(NB), dim3(NTH), 0, stream>>>(scores, deltas, boxes_ws);
    mask_corner_kernel<<<dim3(4, 2, NB), dim3(256), 0, stream>>>(boxes_ws, masks2);
    nms_reduce_kernel<<<dim3(NB), dim3(256), 0, stream>>>(boxes_ws, masks2, (float*)d_out);
  } else {
    rpn_proposal_mono<<<dim3(NB), dim3(NTH), 0, stream>>>(scores, deltas, (float*)d_out);
  }
}